// Round 3
// baseline (360.742 us; speedup 1.0000x reference)
//
#include <hip/hip_runtime.h>
#include <hip/hip_bf16.h>
#include <math.h>

#define E_    8
#define HID_  1024
#define FFN_  2048
#define M_    2048     // B*S
#define NP_   (M_*2)   // total (token, expert) pairs

typedef __attribute__((ext_vector_type(8))) short bf16x8;
typedef __attribute__((ext_vector_type(4))) float f32x4;

typedef const __attribute__((address_space(1))) void GVOID;
typedef __attribute__((address_space(3))) void LVOID;

__device__ __forceinline__ short f2bf(float f) {
    union { __hip_bfloat16 b; short s; } u;
    u.b = __float2bfloat16(f);
    return u.s;
}

// ---------------------------------------------------------------------------
// x (fp32) -> xb (bf16)
// ---------------------------------------------------------------------------
__global__ __launch_bounds__(256) void convert_x_kernel(
    const float* __restrict__ x, __hip_bfloat16* __restrict__ xb)
{
    int i = (blockIdx.x * 256 + threadIdx.x) * 4;
    float4 v = *(const float4*)(x + i);
    short4 o;
    o.x = f2bf(v.x); o.y = f2bf(v.y); o.z = f2bf(v.z); o.w = f2bf(v.w);
    *(short4*)((short*)xb + i) = o;
}

// ---------------------------------------------------------------------------
// Router: one wave per token (unchanged, proven)
// ---------------------------------------------------------------------------
__global__ __launch_bounds__(64) void router_kernel(
    const float* __restrict__ x, const float* __restrict__ rw,
    const float* __restrict__ rb, int* __restrict__ ids,
    float* __restrict__ wts, int* __restrict__ cnt,
    float* __restrict__ topk_out)
{
    const int m    = blockIdx.x;
    const int lane = threadIdx.x;
    const float* xm = x + (size_t)m * HID_;

    float lg[E_];
#pragma unroll
    for (int e = 0; e < E_; ++e) {
        const float* we = rw + e * HID_;
        float s = 0.f;
        for (int k = lane; k < HID_; k += 64) s = fmaf(xm[k], we[k], s);
        lg[e] = s;
    }
#pragma unroll
    for (int off = 32; off; off >>= 1)
#pragma unroll
        for (int e = 0; e < E_; ++e) lg[e] += __shfl_xor(lg[e], off);

    if (lane == 0) {
        float l2[E_], p[E_];
        float mx = -1e30f;
#pragma unroll
        for (int e = 0; e < E_; ++e) { l2[e] = lg[e] + rb[e]; mx = fmaxf(mx, l2[e]); }
        float sum = 0.f;
#pragma unroll
        for (int e = 0; e < E_; ++e) { p[e] = expf(l2[e] - mx); sum += p[e]; }
        float inv = 1.f / sum;
#pragma unroll
        for (int e = 0; e < E_; ++e) p[e] *= inv;

        int   i1 = -1, i2 = -1;
        float v1 = -1e30f, v2 = -1e30f;
#pragma unroll
        for (int e = 0; e < E_; ++e) {
            float pe = p[e];
            if (pe > v1)      { v2 = v1; i2 = i1; v1 = pe; i1 = e; }
            else if (pe > v2) { v2 = pe; i2 = e; }
        }
        ids[2*m]   = i1;  ids[2*m+1]   = i2;
        wts[2*m]   = v1;  wts[2*m+1]   = v2;
        topk_out[2*m]   = v1;
        topk_out[2*m+1] = v2;
        atomicAdd(&cnt[i1], 1);
        atomicAdd(&cnt[i2], 1);
    }
}

__global__ void offsets_kernel(const int* __restrict__ cnt,
                               int* __restrict__ off, int* __restrict__ fill)
{
    if (threadIdx.x == 0 && blockIdx.x == 0) {
        int acc = 0;
        for (int e = 0; e < E_; ++e) { off[e] = acc; fill[e] = acc; acc += cnt[e]; }
    }
}

__global__ __launch_bounds__(256) void scatter_kernel(
    const int* __restrict__ ids, const float* __restrict__ wts,
    int* __restrict__ fill, int* __restrict__ gtok, float* __restrict__ gwt,
    int* __restrict__ pos)
{
    int m = blockIdx.x * 256 + threadIdx.x;
    if (m >= M_) return;
#pragma unroll
    for (int s = 0; s < 2; ++s) {
        int e = ids[2*m + s];
        int p = atomicAdd(&fill[e], 1);
        gtok[p] = m;
        gwt[p]  = wts[2*m + s];
        pos[2*m + s] = p;
    }
}

// ---------------------------------------------------------------------------
// GEMM1 (MFMA bf16, 2-phase dbuf): 128 gathered tokens x 64 h-cols per block.
// ---------------------------------------------------------------------------
__global__ __launch_bounds__(256, 2) void gemm1_kernel(
    const __hip_bfloat16* __restrict__ xb, const float* __restrict__ w1,
    const float* __restrict__ w1b, const int* __restrict__ gtok,
    const int* __restrict__ cnt, const int* __restrict__ off,
    __hip_bfloat16* __restrict__ h)
{
    const int e  = blockIdx.z;
    const int ce = cnt[e];
    const int t0 = blockIdx.y * 128;
    if (t0 >= ce) return;
    const int n0   = blockIdx.x * 64;
    const int base = off[e];
    const float* w1e = w1 + (size_t)e * (2*FFN_) * HID_;

    __shared__ __align__(16) __hip_bfloat16 As[2][128*64];
    __shared__ __align__(16) __hip_bfloat16 Bs[2][128*64];

    const int tid  = threadIdx.x;
    const int lane = tid & 63;
    const int wid  = tid >> 6;
    const int wm   = wid >> 1;
    const int wn   = wid & 1;

    const __hip_bfloat16* asrc[4];
#pragma unroll
    for (int q = 0; q < 4; ++q) {
        int slot = q*256 + tid;
        int r = slot >> 3, p = slot & 7;
        int rr  = min(t0 + r, ce - 1);
        int tok = gtok[base + rr];
        int c = p ^ (r & 7);               // inverse-swizzled source chunk
        asrc[q] = xb + (size_t)tok * HID_ + c*8;
    }

    const int brow = tid >> 1;
    const int hk   = tid & 1;
    const int q2 = brow >> 5, s = brow & 31;
    const int grow = (q2 & 1) ? (FFN_ + n0 + (q2>>1)*32 + s)
                              : (       n0 + (q2>>1)*32 + s);
    const float* bsrc = w1e + (size_t)grow * HID_ + hk*32;

    f32x4 acc[4][4];
#pragma unroll
    for (int m = 0; m < 4; ++m)
#pragma unroll
        for (int n = 0; n < 4; ++n) acc[m][n] = (f32x4){0.f,0.f,0.f,0.f};

    float4 breg[8];
#pragma unroll
    for (int j = 0; j < 8; ++j) breg[j] = *(const float4*)(bsrc + j*4);

    auto STAGE_A = [&](int b, int k0) {
#pragma unroll
        for (int q = 0; q < 4; ++q)
            __builtin_amdgcn_global_load_lds(
                (GVOID*)(asrc[q] + k0),
                (LVOID*)(&As[b][(q*256 + wid*64)*8]), 16, 0, 0);
    };
    auto WRITE_B = [&](int b) {
#pragma unroll
        for (int cc = 0; cc < 4; ++cc) {
            union { bf16x8 v; short s8[8]; } u;
            const float* f0 = (const float*)&breg[2*cc];
#pragma unroll
            for (int j = 0; j < 8; ++j) u.s8[j] = f2bf(f0[j]);
            int c = hk*4 + cc, p = c ^ (brow & 7);
            *(bf16x8*)&Bs[b][brow*64 + p*8] = u.v;
        }
    };
    auto LOAD_B = [&](int k0) {
#pragma unroll
        for (int j = 0; j < 8; ++j) breg[j] = *(const float4*)(bsrc + k0 + j*4);
    };

    // prologue: tile 0 staged, breg <- tile 1
    STAGE_A(0, 0);
    WRITE_B(0);
    LOAD_B(64);
    __syncthreads();

    const int NT = HID_/64;   // 16
    for (int t = 0; t < NT-1; ++t) {
        const int cur = t & 1, nxt = cur ^ 1;
        STAGE_A(nxt, (t+1)*64);

        bf16x8 af[4][2], bfr[4][2];
#pragma unroll
        for (int m = 0; m < 4; ++m)
#pragma unroll
            for (int kk = 0; kk < 2; ++kk) {
                int r = wm*64 + m*16 + (lane & 15);
                int c = kk*4 + (lane >> 4), p = c ^ (r & 7);
                af[m][kk] = *(bf16x8*)&As[cur][r*64 + p*8];
            }
#pragma unroll
        for (int n = 0; n < 4; ++n)
#pragma unroll
            for (int kk = 0; kk < 2; ++kk) {
                int r = wn*64 + n*16 + (lane & 15);
                int c = kk*4 + (lane >> 4), p = c ^ (r & 7);
                bfr[n][kk] = *(bf16x8*)&Bs[cur][r*64 + p*8];
            }

        WRITE_B(nxt);                     // breg holds tile t+1
        if (t < NT-2) LOAD_B((t+2)*64);   // prefetch tile t+2

        __builtin_amdgcn_s_setprio(1);
#pragma unroll
        for (int kk = 0; kk < 2; ++kk)
#pragma unroll
            for (int m = 0; m < 4; ++m)
#pragma unroll
                for (int n = 0; n < 4; ++n)
                    acc[m][n] = __builtin_amdgcn_mfma_f32_16x16x32_bf16(
                        af[m][kk], bfr[n][kk], acc[m][n], 0, 0, 0);
        __builtin_amdgcn_s_setprio(0);
        __syncthreads();
    }

    {   // final tile (buf 1)
        bf16x8 af[4][2], bfr[4][2];
#pragma unroll
        for (int m = 0; m < 4; ++m)
#pragma unroll
            for (int kk = 0; kk < 2; ++kk) {
                int r = wm*64 + m*16 + (lane & 15);
                int c = kk*4 + (lane >> 4), p = c ^ (r & 7);
                af[m][kk] = *(bf16x8*)&As[1][r*64 + p*8];
            }
#pragma unroll
        for (int n = 0; n < 4; ++n)
#pragma unroll
            for (int kk = 0; kk < 2; ++kk) {
                int r = wn*64 + n*16 + (lane & 15);
                int c = kk*4 + (lane >> 4), p = c ^ (r & 7);
                bfr[n][kk] = *(bf16x8*)&Bs[1][r*64 + p*8];
            }
        __builtin_amdgcn_s_setprio(1);
#pragma unroll
        for (int kk = 0; kk < 2; ++kk)
#pragma unroll
            for (int m = 0; m < 4; ++m)
#pragma unroll
                for (int n = 0; n < 4; ++n)
                    acc[m][n] = __builtin_amdgcn_mfma_f32_16x16x32_bf16(
                        af[m][kk], bfr[n][kk], acc[m][n], 0, 0, 0);
        __builtin_amdgcn_s_setprio(0);
    }

    // Epilogue: fused SiLU(gate)*up -> h (bf16)
    const float* w1be = w1b + e*2*FFN_;
#pragma unroll
    for (int n = 0; n < 2; ++n) {
        int col = n0 + wn*32 + n*16 + (lane & 15);
        float bg = w1be[col];
        float bu = w1be[FFN_ + col];
#pragma unroll
        for (int m = 0; m < 4; ++m) {
            int rb2 = t0 + wm*64 + m*16 + (lane >> 4)*4;
#pragma unroll
            for (int i = 0; i < 4; ++i) {
                int t = rb2 + i;
                if (t < ce) {
                    float g = acc[m][n][i]   + bg;
                    float u = acc[m][n+2][i] + bu;
                    float hv = (g / (1.f + __expf(-g))) * u;
                    h[(size_t)(base + t)*FFN_ + col] = __float2bfloat16(hv);
                }
            }
        }
    }
}

// ---------------------------------------------------------------------------
// GEMM2 (MFMA bf16, 2-phase dbuf): 128 pairs x 128 hid cols per block.
// dpair != nullptr: plain stores to per-pair buffer (combine kernel sums).
// dpair == nullptr: atomicAdd fallback into out.
// ---------------------------------------------------------------------------
__global__ __launch_bounds__(256, 2) void gemm2_kernel(
    const __hip_bfloat16* __restrict__ h, const float* __restrict__ w2,
    const float* __restrict__ w2b, const int* __restrict__ gtok,
    const float* __restrict__ gwt, const int* __restrict__ cnt,
    const int* __restrict__ off, float* __restrict__ out,
    float* __restrict__ dpair)
{
    const int e  = blockIdx.z;
    const int ce = cnt[e];
    const int t0 = blockIdx.y * 128;
    if (t0 >= ce) return;
    const int n0   = blockIdx.x * 128;
    const int base = off[e];
    const float* w2e = w2 + (size_t)e * HID_ * FFN_;

    __shared__ __align__(16) __hip_bfloat16 As[2][128*64];
    __shared__ __align__(16) __hip_bfloat16 Bs[2][128*64];

    const int tid  = threadIdx.x;
    const int lane = tid & 63;
    const int wid  = tid >> 6;
    const int wm   = wid >> 1;
    const int wn   = wid & 1;

    const __hip_bfloat16* asrc[4];
#pragma unroll
    for (int q = 0; q < 4; ++q) {
        int slot = q*256 + tid;
        int r = slot >> 3, p = slot & 7;
        int rr = min(t0 + r, ce - 1);
        int c = p ^ (r & 7);
        asrc[q] = h + (size_t)(base + rr) * FFN_ + c*8;
    }

    const int brow = tid >> 1;
    const int hk   = tid & 1;
    const float* bsrc = w2e + (size_t)(n0 + brow) * FFN_ + hk*32;

    f32x4 acc[4][4];
#pragma unroll
    for (int m = 0; m < 4; ++m)
#pragma unroll
        for (int n = 0; n < 4; ++n) acc[m][n] = (f32x4){0.f,0.f,0.f,0.f};

    float4 breg[8];
#pragma unroll
    for (int j = 0; j < 8; ++j) breg[j] = *(const float4*)(bsrc + j*4);

    auto STAGE_A = [&](int b, int k0) {
#pragma unroll
        for (int q = 0; q < 4; ++q)
            __builtin_amdgcn_global_load_lds(
                (GVOID*)(asrc[q] + k0),
                (LVOID*)(&As[b][(q*256 + wid*64)*8]), 16, 0, 0);
    };
    auto WRITE_B = [&](int b) {
#pragma unroll
        for (int cc = 0; cc < 4; ++cc) {
            union { bf16x8 v; short s8[8]; } u;
            const float* f0 = (const float*)&breg[2*cc];
#pragma unroll
            for (int j = 0; j < 8; ++j) u.s8[j] = f2bf(f0[j]);
            int c = hk*4 + cc, p = c ^ (brow & 7);
            *(bf16x8*)&Bs[b][brow*64 + p*8] = u.v;
        }
    };
    auto LOAD_B = [&](int k0) {
#pragma unroll
        for (int j = 0; j < 8; ++j) breg[j] = *(const float4*)(bsrc + k0 + j*4);
    };

    STAGE_A(0, 0);
    WRITE_B(0);
    LOAD_B(64);
    __syncthreads();

    const int NT = FFN_/64;   // 32
    for (int t = 0; t < NT-1; ++t) {
        const int cur = t & 1, nxt = cur ^ 1;
        STAGE_A(nxt, (t+1)*64);

        bf16x8 af[4][2], bfr[4][2];
#pragma unroll
        for (int m = 0; m < 4; ++m)
#pragma unroll
            for (int kk = 0; kk < 2; ++kk) {
                int r = wm*64 + m*16 + (lane & 15);
                int c = kk*4 + (lane >> 4), p = c ^ (r & 7);
                af[m][kk] = *(bf16x8*)&As[cur][r*64 + p*8];
            }
#pragma unroll
        for (int n = 0; n < 4; ++n)
#pragma unroll
            for (int kk = 0; kk < 2; ++kk) {
                int r = wn*64 + n*16 + (lane & 15);
                int c = kk*4 + (lane >> 4), p = c ^ (r & 7);
                bfr[n][kk] = *(bf16x8*)&Bs[cur][r*64 + p*8];
            }

        WRITE_B(nxt);
        if (t < NT-2) LOAD_B((t+2)*64);

        __builtin_amdgcn_s_setprio(1);
#pragma unroll
        for (int kk = 0; kk < 2; ++kk)
#pragma unroll
            for (int m = 0; m < 4; ++m)
#pragma unroll
                for (int n = 0; n < 4; ++n)
                    acc[m][n] = __builtin_amdgcn_mfma_f32_16x16x32_bf16(
                        af[m][kk], bfr[n][kk], acc[m][n], 0, 0, 0);
        __builtin_amdgcn_s_setprio(0);
        __syncthreads();
    }

    {   // final tile (buf 1)
        bf16x8 af[4][2], bfr[4][2];
#pragma unroll
        for (int m = 0; m < 4; ++m)
#pragma unroll
            for (int kk = 0; kk < 2; ++kk) {
                int r = wm*64 + m*16 + (lane & 15);
                int c = kk*4 + (lane >> 4), p = c ^ (r & 7);
                af[m][kk] = *(bf16x8*)&As[1][r*64 + p*8];
            }
#pragma unroll
        for (int n = 0; n < 4; ++n)
#pragma unroll
            for (int kk = 0; kk < 2; ++kk) {
                int r = wn*64 + n*16 + (lane & 15);
                int c = kk*4 + (lane >> 4), p = c ^ (r & 7);
                bfr[n][kk] = *(bf16x8*)&Bs[1][r*64 + p*8];
            }
        __builtin_amdgcn_s_setprio(1);
#pragma unroll
        for (int kk = 0; kk < 2; ++kk)
#pragma unroll
            for (int m = 0; m < 4; ++m)
#pragma unroll
                for (int n = 0; n < 4; ++n)
                    acc[m][n] = __builtin_amdgcn_mfma_f32_16x16x32_bf16(
                        af[m][kk], bfr[n][kk], acc[m][n], 0, 0, 0);
        __builtin_amdgcn_s_setprio(0);
    }

    const float* w2be = w2b + e*HID_;
#pragma unroll
    for (int n = 0; n < 4; ++n) {
        int col = n0 + wn*64 + n*16 + (lane & 15);
        float bias = w2be[col];
#pragma unroll
        for (int m = 0; m < 4; ++m) {
            int rb2 = t0 + wm*64 + m*16 + (lane >> 4)*4;
#pragma unroll
            for (int i = 0; i < 4; ++i) {
                int t = rb2 + i;
                if (t < ce) {
                    int p   = base + t;
                    float w = gwt[p];
                    float v = w * (acc[m][n][i] + bias);
                    if (dpair) dpair[(size_t)p*HID_ + col] = v;
                    else       atomicAdd(&out[(size_t)gtok[p]*HID_ + col], v);
                }
            }
        }
    }
}

// ---------------------------------------------------------------------------
// out[m][c] = dpair[pos[2m]][c] + dpair[pos[2m+1]][c]
// ---------------------------------------------------------------------------
__global__ __launch_bounds__(256) void combine_kernel(
    const float* __restrict__ dpair, const int* __restrict__ pos,
    float* __restrict__ out)
{
    int idx = blockIdx.x * 256 + threadIdx.x;
    int m   = idx >> 8;                 // HID/4 = 256 chunks per token
    int c4  = (idx & 255) * 4;
    int p0 = pos[2*m], p1 = pos[2*m+1];
    float4 a = *(const float4*)(dpair + (size_t)p0*HID_ + c4);
    float4 b = *(const float4*)(dpair + (size_t)p1*HID_ + c4);
    float4 o = make_float4(a.x+b.x, a.y+b.y, a.z+b.z, a.w+b.w);
    *(float4*)(out + (size_t)m*HID_ + c4) = o;
}

// ---------------------------------------------------------------------------
extern "C" void kernel_launch(void* const* d_in, const int* in_sizes, int n_in,
                              void* d_out, int out_size, void* d_ws, size_t ws_size,
                              hipStream_t stream)
{
    const float* x   = (const float*)d_in[0];
    const float* rw  = (const float*)d_in[1];
    const float* rb  = (const float*)d_in[2];
    const float* w1  = (const float*)d_in[3];
    const float* w1b = (const float*)d_in[4];
    const float* w2  = (const float*)d_in[5];
    const float* w2b = (const float*)d_in[6];

    float* out      = (float*)d_out;
    float* topk_out = out + (size_t)M_ * HID_;

    char*  ws   = (char*)d_ws;
    int*   ids  = (int*)  (ws);
    float* wts  = (float*)(ws + 16384);
    int*   gtok = (int*)  (ws + 32768);
    float* gwt  = (float*)(ws + 49152);
    int*   cnt  = (int*)  (ws + 65536);
    int*   off  = (int*)  (ws + 65536 + 128);
    int*   fill = (int*)  (ws + 65536 + 256);
    int*   pos  = (int*)  (ws + 98304);                                  // 16 KB
    __hip_bfloat16* xb = (__hip_bfloat16*)(ws + 131072);                 // 4 MB
    __hip_bfloat16* h  = (__hip_bfloat16*)(ws + 131072 + 4*1024*1024);   // 16 MB
    float* dpair = (float*)(ws + 131072 + 20*1024*1024);                 // 16 MB

    const size_t need = 131072 + (size_t)(4+16+16)*1024*1024;
    const bool use_dpair = (ws_size >= need);

    hipMemsetAsync(cnt, 0, E_ * sizeof(int), stream);
    if (!use_dpair)
        hipMemsetAsync(out, 0, (size_t)M_ * HID_ * sizeof(float), stream);

    convert_x_kernel<<<(M_*HID_)/(256*4), 256, 0, stream>>>(x, xb);
    router_kernel<<<M_, 64, 0, stream>>>(x, rw, rb, ids, wts, cnt, topk_out);
    offsets_kernel<<<1, 64, 0, stream>>>(cnt, off, fill);
    scatter_kernel<<<M_/256, 256, 0, stream>>>(ids, wts, fill, gtok, gwt, pos);

    dim3 g1(FFN_/64, M_/128, E_);    // (32, 16, 8)
    gemm1_kernel<<<g1, 256, 0, stream>>>(xb, w1, w1b, gtok, cnt, off, h);

    dim3 g2(HID_/128, M_/128, E_);   // (8, 16, 8)
    gemm2_kernel<<<g2, 256, 0, stream>>>(h, w2, w2b, gtok, gwt, cnt, off, out,
                                         use_dpair ? dpair : nullptr);

    if (use_dpair)
        combine_kernel<<<(M_*HID_)/(256*4), 256, 0, stream>>>(dpair, pos, out);
}

// Round 4
// 319.299 us; speedup vs baseline: 1.1298x; 1.1298x over previous
//
#include <hip/hip_runtime.h>
#include <hip/hip_bf16.h>
#include <math.h>

#define E_    8
#define HID_  1024
#define FFN_  2048
#define M_    2048     // B*S
#define NP_   (M_*2)   // total (token, expert) pairs

typedef __attribute__((ext_vector_type(8))) short bf16x8;
typedef __attribute__((ext_vector_type(4))) float f32x4;

typedef const __attribute__((address_space(1))) void GVOID;
typedef __attribute__((address_space(3))) void LVOID;

__device__ __forceinline__ short f2bf(float f) {
    union { __hip_bfloat16 b; short s; } u;
    u.b = __float2bfloat16(f);
    return u.s;
}

// ---------------------------------------------------------------------------
// fp32 -> bf16 elementwise (grid-stride, float4 in / short4 out)
// ---------------------------------------------------------------------------
__global__ __launch_bounds__(256) void cvt_kernel(
    const float* __restrict__ src, __hip_bfloat16* __restrict__ dst, int n4)
{
    int stride = gridDim.x * 256;
    for (int i = blockIdx.x * 256 + threadIdx.x; i < n4; i += stride) {
        float4 v = ((const float4*)src)[i];
        short4 o;
        o.x = f2bf(v.x); o.y = f2bf(v.y); o.z = f2bf(v.z); o.w = f2bf(v.w);
        ((short4*)dst)[i] = o;
    }
}

// ---------------------------------------------------------------------------
// Router: one wave per token (proven)
// ---------------------------------------------------------------------------
__global__ __launch_bounds__(64) void router_kernel(
    const float* __restrict__ x, const float* __restrict__ rw,
    const float* __restrict__ rb, int* __restrict__ ids,
    float* __restrict__ wts, int* __restrict__ cnt,
    float* __restrict__ topk_out)
{
    const int m    = blockIdx.x;
    const int lane = threadIdx.x;
    const float* xm = x + (size_t)m * HID_;

    float lg[E_];
#pragma unroll
    for (int e = 0; e < E_; ++e) {
        const float* we = rw + e * HID_;
        float s = 0.f;
        for (int k = lane; k < HID_; k += 64) s = fmaf(xm[k], we[k], s);
        lg[e] = s;
    }
#pragma unroll
    for (int off = 32; off; off >>= 1)
#pragma unroll
        for (int e = 0; e < E_; ++e) lg[e] += __shfl_xor(lg[e], off);

    if (lane == 0) {
        float l2[E_], p[E_];
        float mx = -1e30f;
#pragma unroll
        for (int e = 0; e < E_; ++e) { l2[e] = lg[e] + rb[e]; mx = fmaxf(mx, l2[e]); }
        float sum = 0.f;
#pragma unroll
        for (int e = 0; e < E_; ++e) { p[e] = expf(l2[e] - mx); sum += p[e]; }
        float inv = 1.f / sum;
#pragma unroll
        for (int e = 0; e < E_; ++e) p[e] *= inv;

        int   i1 = -1, i2 = -1;
        float v1 = -1e30f, v2 = -1e30f;
#pragma unroll
        for (int e = 0; e < E_; ++e) {
            float pe = p[e];
            if (pe > v1)      { v2 = v1; i2 = i1; v1 = pe; i1 = e; }
            else if (pe > v2) { v2 = pe; i2 = e; }
        }
        ids[2*m]   = i1;  ids[2*m+1]   = i2;
        wts[2*m]   = v1;  wts[2*m+1]   = v2;
        topk_out[2*m]   = v1;
        topk_out[2*m+1] = v2;
        atomicAdd(&cnt[i1], 1);
        atomicAdd(&cnt[i2], 1);
    }
}

__global__ void offsets_kernel(const int* __restrict__ cnt,
                               int* __restrict__ off, int* __restrict__ fill)
{
    if (threadIdx.x == 0 && blockIdx.x == 0) {
        int acc = 0;
        for (int e = 0; e < E_; ++e) { off[e] = acc; fill[e] = acc; acc += cnt[e]; }
    }
}

__global__ __launch_bounds__(256) void scatter_kernel(
    const int* __restrict__ ids, const float* __restrict__ wts,
    int* __restrict__ fill, int* __restrict__ gtok, float* __restrict__ gwt,
    int* __restrict__ pos)
{
    int m = blockIdx.x * 256 + threadIdx.x;
    if (m >= M_) return;
#pragma unroll
    for (int s = 0; s < 2; ++s) {
        int e = ids[2*m + s];
        int p = atomicAdd(&fill[e], 1);
        gtok[p] = m;
        gwt[p]  = wts[2*m + s];
        pos[2*m + s] = p;
    }
}

// ===========================================================================
// TIER-2 GEMMs: bf16 weights, both operands via global_load_lds, BK=32,
// double-buffered, ONE barrier per K-step (T3 minimum 2-phase).
// LDS swizzle: 16B chunk p of row r holds global chunk p ^ ((r>>1)&3)
// (applied on stage SOURCE addr and on frag-read addr; 2-way conflicts only).
// ===========================================================================

// GEMM1: 128 gathered tokens x 64 h-cols (128 gu rows, gate/up interleaved
// in 32-row groups). K = HID = 1024, 32 steps.
__global__ __launch_bounds__(256, 3) void gemm1_kernel(
    const __hip_bfloat16* __restrict__ xb, const __hip_bfloat16* __restrict__ w1bf,
    const float* __restrict__ w1b, const int* __restrict__ gtok,
    const int* __restrict__ cnt, const int* __restrict__ off,
    __hip_bfloat16* __restrict__ h)
{
    const int e  = blockIdx.z;
    const int ce = cnt[e];
    const int t0 = blockIdx.y * 128;
    if (t0 >= ce) return;
    const int n0   = blockIdx.x * 64;
    const int base = off[e];
    const __hip_bfloat16* w1e = w1bf + (size_t)e * (2*FFN_) * HID_;

    __shared__ __align__(16) __hip_bfloat16 As[2][128*32];
    __shared__ __align__(16) __hip_bfloat16 Bs[2][128*32];

    const int tid  = threadIdx.x;
    const int lane = tid & 63;
    const int wid  = tid >> 6;
    const int wm   = wid >> 1;
    const int wn   = wid & 1;

    // per-thread stage sources: 2 x 16B slots for A, 2 for B
    const __hip_bfloat16 *asrc[2], *bsrc[2];
#pragma unroll
    for (int q = 0; q < 2; ++q) {
        int slot = q*256 + tid;
        int r = slot >> 2, p = slot & 3;
        int c = p ^ ((r >> 1) & 3);
        int rr  = min(t0 + r, ce - 1);
        asrc[q] = xb + (size_t)gtok[base + rr] * HID_ + c*8;
        int q2 = r >> 5, s = r & 31;
        int grow = (q2 & 1) ? (FFN_ + n0 + (q2>>1)*32 + s)
                            : (       n0 + (q2>>1)*32 + s);
        bsrc[q] = w1e + (size_t)grow * HID_ + c*8;
    }

    auto STAGE = [&](int b, int k0) {
#pragma unroll
        for (int q = 0; q < 2; ++q)
            __builtin_amdgcn_global_load_lds((GVOID*)(asrc[q] + k0),
                (LVOID*)(&As[b][(q*256 + wid*64)*8]), 16, 0, 0);
#pragma unroll
        for (int q = 0; q < 2; ++q)
            __builtin_amdgcn_global_load_lds((GVOID*)(bsrc[q] + k0),
                (LVOID*)(&Bs[b][(q*256 + wid*64)*8]), 16, 0, 0);
    };

    f32x4 acc[4][4];
#pragma unroll
    for (int m = 0; m < 4; ++m)
#pragma unroll
        for (int n = 0; n < 4; ++n) acc[m][n] = (f32x4){0.f,0.f,0.f,0.f};

    STAGE(0, 0);
    __syncthreads();

    const int NT = HID_/32;   // 32
    const int cf = lane >> 4;
    for (int t = 0; t < NT; ++t) {
        const int cur = t & 1, nxt = cur ^ 1;
        if (t + 1 < NT) STAGE(nxt, (t+1)*32);

        bf16x8 af[4], bfr[4];
#pragma unroll
        for (int m = 0; m < 4; ++m) {
            int r = wm*64 + m*16 + (lane & 15);
            int sw = cf ^ ((r >> 1) & 3);
            af[m] = *(bf16x8*)&As[cur][r*32 + sw*8];
        }
#pragma unroll
        for (int n = 0; n < 4; ++n) {
            int r = wn*64 + n*16 + (lane & 15);
            int sw = cf ^ ((r >> 1) & 3);
            bfr[n] = *(bf16x8*)&Bs[cur][r*32 + sw*8];
        }
        __builtin_amdgcn_s_setprio(1);
#pragma unroll
        for (int m = 0; m < 4; ++m)
#pragma unroll
            for (int n = 0; n < 4; ++n)
                acc[m][n] = __builtin_amdgcn_mfma_f32_16x16x32_bf16(
                    af[m], bfr[n], acc[m][n], 0, 0, 0);
        __builtin_amdgcn_s_setprio(0);
        __syncthreads();
    }

    // Epilogue: fused SiLU(gate)*up -> h (bf16)  [unchanged, validated]
    const float* w1be = w1b + e*2*FFN_;
#pragma unroll
    for (int n = 0; n < 2; ++n) {
        int col = n0 + wn*32 + n*16 + (lane & 15);
        float bg = w1be[col];
        float bu = w1be[FFN_ + col];
#pragma unroll
        for (int m = 0; m < 4; ++m) {
            int rb2 = t0 + wm*64 + m*16 + (lane >> 4)*4;
#pragma unroll
            for (int i = 0; i < 4; ++i) {
                int t = rb2 + i;
                if (t < ce) {
                    float g = acc[m][n][i]   + bg;
                    float u = acc[m][n+2][i] + bu;
                    float hv = (g / (1.f + __expf(-g))) * u;
                    h[(size_t)(base + t)*FFN_ + col] = __float2bfloat16(hv);
                }
            }
        }
    }
}

// GEMM2: 128 pairs x 128 hid cols, split-K=2 (z = e + 8*ks), K-half = 1024,
// 32 steps. Epilogue atomicAdd into zeroed dpair (2 commutative addends).
__global__ __launch_bounds__(256, 3) void gemm2_kernel(
    const __hip_bfloat16* __restrict__ h, const __hip_bfloat16* __restrict__ w2bf,
    const float* __restrict__ w2b, const float* __restrict__ gwt,
    const int* __restrict__ cnt, const int* __restrict__ off,
    float* __restrict__ dpair)
{
    const int e  = blockIdx.z & 7;
    const int ks = blockIdx.z >> 3;
    const int ce = cnt[e];
    const int t0 = blockIdx.y * 128;
    if (t0 >= ce) return;
    const int n0    = blockIdx.x * 128;
    const int base  = off[e];
    const int kbase = ks * (FFN_/2);
    const __hip_bfloat16* w2e = w2bf + (size_t)e * HID_ * FFN_;

    __shared__ __align__(16) __hip_bfloat16 As[2][128*32];
    __shared__ __align__(16) __hip_bfloat16 Bs[2][128*32];

    const int tid  = threadIdx.x;
    const int lane = tid & 63;
    const int wid  = tid >> 6;
    const int wm   = wid >> 1;
    const int wn   = wid & 1;

    const __hip_bfloat16 *asrc[2], *bsrc[2];
#pragma unroll
    for (int q = 0; q < 2; ++q) {
        int slot = q*256 + tid;
        int r = slot >> 2, p = slot & 3;
        int c = p ^ ((r >> 1) & 3);
        int rr = min(t0 + r, ce - 1);
        asrc[q] = h   + (size_t)(base + rr) * FFN_ + kbase + c*8;
        bsrc[q] = w2e + (size_t)(n0 + r)    * FFN_ + kbase + c*8;
    }

    auto STAGE = [&](int b, int k0) {
#pragma unroll
        for (int q = 0; q < 2; ++q)
            __builtin_amdgcn_global_load_lds((GVOID*)(asrc[q] + k0),
                (LVOID*)(&As[b][(q*256 + wid*64)*8]), 16, 0, 0);
#pragma unroll
        for (int q = 0; q < 2; ++q)
            __builtin_amdgcn_global_load_lds((GVOID*)(bsrc[q] + k0),
                (LVOID*)(&Bs[b][(q*256 + wid*64)*8]), 16, 0, 0);
    };

    f32x4 acc[4][4];
#pragma unroll
    for (int m = 0; m < 4; ++m)
#pragma unroll
        for (int n = 0; n < 4; ++n) acc[m][n] = (f32x4){0.f,0.f,0.f,0.f};

    STAGE(0, 0);
    __syncthreads();

    const int NT = (FFN_/2)/32;   // 32
    const int cf = lane >> 4;
    for (int t = 0; t < NT; ++t) {
        const int cur = t & 1, nxt = cur ^ 1;
        if (t + 1 < NT) STAGE(nxt, (t+1)*32);

        bf16x8 af[4], bfr[4];
#pragma unroll
        for (int m = 0; m < 4; ++m) {
            int r = wm*64 + m*16 + (lane & 15);
            int sw = cf ^ ((r >> 1) & 3);
            af[m] = *(bf16x8*)&As[cur][r*32 + sw*8];
        }
#pragma unroll
        for (int n = 0; n < 4; ++n) {
            int r = wn*64 + n*16 + (lane & 15);
            int sw = cf ^ ((r >> 1) & 3);
            bfr[n] = *(bf16x8*)&Bs[cur][r*32 + sw*8];
        }
        __builtin_amdgcn_s_setprio(1);
#pragma unroll
        for (int m = 0; m < 4; ++m)
#pragma unroll
            for (int n = 0; n < 4; ++n)
                acc[m][n] = __builtin_amdgcn_mfma_f32_16x16x32_bf16(
                    af[m], bfr[n], acc[m][n], 0, 0, 0);
        __builtin_amdgcn_s_setprio(0);
        __syncthreads();
    }

    const float* w2be = w2b + e*HID_;
#pragma unroll
    for (int n = 0; n < 4; ++n) {
        int col = n0 + wn*64 + n*16 + (lane & 15);
        float bias = (ks == 0) ? w2be[col] : 0.f;
#pragma unroll
        for (int m = 0; m < 4; ++m) {
            int rb2 = t0 + wm*64 + m*16 + (lane >> 4)*4;
#pragma unroll
            for (int i = 0; i < 4; ++i) {
                int t = rb2 + i;
                if (t < ce) {
                    int p   = base + t;
                    float w = gwt[p];
                    atomicAdd(&dpair[(size_t)p*HID_ + col], w * (acc[m][n][i] + bias));
                }
            }
        }
    }
}

// out[m][c] = dpair[pos[2m]][c] + dpair[pos[2m+1]][c]
__global__ __launch_bounds__(256) void combine_kernel(
    const float* __restrict__ dpair, const int* __restrict__ pos,
    float* __restrict__ out)
{
    int idx = blockIdx.x * 256 + threadIdx.x;
    int m   = idx >> 8;
    int c4  = (idx & 255) * 4;
    int p0 = pos[2*m], p1 = pos[2*m+1];
    float4 a = *(const float4*)(dpair + (size_t)p0*HID_ + c4);
    float4 b = *(const float4*)(dpair + (size_t)p1*HID_ + c4);
    float4 o = make_float4(a.x+b.x, a.y+b.y, a.z+b.z, a.w+b.w);
    *(float4*)(out + (size_t)m*HID_ + c4) = o;
}

// ===========================================================================
// FALLBACK (round-2 exact, proven): reg-staged fp32 weights, single buffer.
// Used only when ws_size cannot hold the converted weights.
// ===========================================================================
__global__ __launch_bounds__(256) void gemm1_rs_kernel(
    const __hip_bfloat16* __restrict__ xb, const float* __restrict__ w1,
    const float* __restrict__ w1b, const int* __restrict__ gtok,
    const int* __restrict__ cnt, const int* __restrict__ off,
    __hip_bfloat16* __restrict__ h)
{
    const int e  = blockIdx.z;
    const int ce = cnt[e];
    const int t0 = blockIdx.y * 128;
    if (t0 >= ce) return;
    const int n0   = blockIdx.x * 64;
    const int base = off[e];
    const float* w1e = w1 + (size_t)e * (2*FFN_) * HID_;

    __shared__ __align__(16) __hip_bfloat16 As[128*64];
    __shared__ __align__(16) __hip_bfloat16 Bs[128*64];

    const int tid  = threadIdx.x;
    const int lane = tid & 63;
    const int wid  = tid >> 6;
    const int wm   = wid >> 1;
    const int wn   = wid & 1;

    const __hip_bfloat16* asrc[4];
#pragma unroll
    for (int q = 0; q < 4; ++q) {
        int slot = q*256 + tid;
        int r = slot >> 3, p = slot & 7;
        int rr  = min(t0 + r, ce - 1);
        int tok = gtok[base + rr];
        int c = p ^ (r & 7);
        asrc[q] = xb + (size_t)tok * HID_ + c*8;
    }

    const int brow = tid >> 1;
    const int hk   = tid & 1;
    const int q2 = brow >> 5, s = brow & 31;
    const int grow = (q2 & 1) ? (FFN_ + n0 + (q2>>1)*32 + s)
                              : (       n0 + (q2>>1)*32 + s);
    const float* bsrc = w1e + (size_t)grow * HID_ + hk*32;

    f32x4 acc[4][4];
#pragma unroll
    for (int m = 0; m < 4; ++m)
#pragma unroll
        for (int n = 0; n < 4; ++n) acc[m][n] = (f32x4){0.f,0.f,0.f,0.f};

    float4 breg[8];
#pragma unroll
    for (int j = 0; j < 8; ++j) breg[j] = *(const float4*)(bsrc + j*4);

    for (int k0 = 0; k0 < HID_; k0 += 64) {
#pragma unroll
        for (int q = 0; q < 4; ++q) {
            __builtin_amdgcn_global_load_lds(
                (GVOID*)(asrc[q] + k0),
                (LVOID*)(&As[(q*256 + wid*64)*8]), 16, 0, 0);
        }
#pragma unroll
        for (int cc = 0; cc < 4; ++cc) {
            union { bf16x8 v; short s8[8]; } u;
            const float* f0 = (const float*)&breg[2*cc];
#pragma unroll
            for (int j = 0; j < 8; ++j) u.s8[j] = f2bf(f0[j]);
            int c = hk*4 + cc, p = c ^ (brow & 7);
            *(bf16x8*)&Bs[brow*64 + p*8] = u.v;
        }
        __syncthreads();

        if (k0 + 64 < HID_) {
#pragma unroll
            for (int j = 0; j < 8; ++j) breg[j] = *(const float4*)(bsrc + (k0+64) + j*4);
        }

        bf16x8 af[4][2], bfr[4][2];
#pragma unroll
        for (int m = 0; m < 4; ++m)
#pragma unroll
            for (int kk = 0; kk < 2; ++kk) {
                int r = wm*64 + m*16 + (lane & 15);
                int c = kk*4 + (lane >> 4), p = c ^ (r & 7);
                af[m][kk] = *(bf16x8*)&As[r*64 + p*8];
            }
#pragma unroll
        for (int n = 0; n < 4; ++n)
#pragma unroll
            for (int kk = 0; kk < 2; ++kk) {
                int r = wn*64 + n*16 + (lane & 15);
                int c = kk*4 + (lane >> 4), p = c ^ (r & 7);
                bfr[n][kk] = *(bf16x8*)&Bs[r*64 + p*8];
            }
#pragma unroll
        for (int kk = 0; kk < 2; ++kk)
#pragma unroll
            for (int m = 0; m < 4; ++m)
#pragma unroll
                for (int n = 0; n < 4; ++n)
                    acc[m][n] = __builtin_amdgcn_mfma_f32_16x16x32_bf16(
                        af[m][kk], bfr[n][kk], acc[m][n], 0, 0, 0);
        __syncthreads();
    }

    const float* w1be = w1b + e*2*FFN_;
#pragma unroll
    for (int n = 0; n < 2; ++n) {
        int col = n0 + wn*32 + n*16 + (lane & 15);
        float bg = w1be[col];
        float bu = w1be[FFN_ + col];
#pragma unroll
        for (int m = 0; m < 4; ++m) {
            int rb2 = t0 + wm*64 + m*16 + (lane >> 4)*4;
#pragma unroll
            for (int i = 0; i < 4; ++i) {
                int t = rb2 + i;
                if (t < ce) {
                    float g = acc[m][n][i]   + bg;
                    float u = acc[m][n+2][i] + bu;
                    float hv = (g / (1.f + __expf(-g))) * u;
                    h[(size_t)(base + t)*FFN_ + col] = __float2bfloat16(hv);
                }
            }
        }
    }
}

__global__ __launch_bounds__(256) void gemm2_rs_kernel(
    const __hip_bfloat16* __restrict__ h, const float* __restrict__ w2,
    const float* __restrict__ w2b, const int* __restrict__ gtok,
    const float* __restrict__ gwt, const int* __restrict__ cnt,
    const int* __restrict__ off, float* __restrict__ out)
{
    const int e  = blockIdx.z;
    const int ce = cnt[e];
    const int t0 = blockIdx.y * 128;
    if (t0 >= ce) return;
    const int n0   = blockIdx.x * 128;
    const int base = off[e];
    const float* w2e = w2 + (size_t)e * HID_ * FFN_;

    __shared__ __align__(16) __hip_bfloat16 As[128*64];
    __shared__ __align__(16) __hip_bfloat16 Bs[128*64];

    const int tid  = threadIdx.x;
    const int lane = tid & 63;
    const int wid  = tid >> 6;
    const int wm   = wid >> 1;
    const int wn   = wid & 1;

    const __hip_bfloat16* asrc[4];
#pragma unroll
    for (int q = 0; q < 4; ++q) {
        int slot = q*256 + tid;
        int r = slot >> 3, p = slot & 7;
        int rr = min(t0 + r, ce - 1);
        int c = p ^ (r & 7);
        asrc[q] = h + (size_t)(base + rr) * FFN_ + c*8;
    }

    const int brow = tid >> 1;
    const int hk   = tid & 1;
    const float* bsrc = w2e + (size_t)(n0 + brow) * FFN_ + hk*32;

    f32x4 acc[4][4];
#pragma unroll
    for (int m = 0; m < 4; ++m)
#pragma unroll
        for (int n = 0; n < 4; ++n) acc[m][n] = (f32x4){0.f,0.f,0.f,0.f};

    float4 breg[8];
#pragma unroll
    for (int j = 0; j < 8; ++j) breg[j] = *(const float4*)(bsrc + j*4);

    for (int k0 = 0; k0 < FFN_; k0 += 64) {
#pragma unroll
        for (int q = 0; q < 4; ++q) {
            __builtin_amdgcn_global_load_lds(
                (GVOID*)(asrc[q] + k0),
                (LVOID*)(&As[(q*256 + wid*64)*8]), 16, 0, 0);
        }
#pragma unroll
        for (int cc = 0; cc < 4; ++cc) {
            union { bf16x8 v; short s8[8]; } u;
            const float* f0 = (const float*)&breg[2*cc];
#pragma unroll
            for (int j = 0; j < 8; ++j) u.s8[j] = f2bf(f0[j]);
            int c = hk*4 + cc, p = c ^ (brow & 7);
            *(bf16x8*)&Bs[brow*64 + p*8] = u.v;
        }
        __syncthreads();

        if (k0 + 64 < FFN_) {
#pragma unroll
            for (int j = 0; j < 8; ++j) breg[j] = *(const float4*)(bsrc + (k0+64) + j*4);
        }

        bf16x8 af[4][2], bfr[4][2];
#pragma unroll
        for (int m = 0; m < 4; ++m)
#pragma unroll
            for (int kk = 0; kk < 2; ++kk) {
                int r = wm*64 + m*16 + (lane & 15);
                int c = kk*4 + (lane >> 4), p = c ^ (r & 7);
                af[m][kk] = *(bf16x8*)&As[r*64 + p*8];
            }
#pragma unroll
        for (int n = 0; n < 4; ++n)
#pragma unroll
            for (int kk = 0; kk < 2; ++kk) {
                int r = wn*64 + n*16 + (lane & 15);
                int c = kk*4 + (lane >> 4), p = c ^ (r & 7);
                bfr[n][kk] = *(bf16x8*)&Bs[r*64 + p*8];
            }
#pragma unroll
        for (int kk = 0; kk < 2; ++kk)
#pragma unroll
            for (int m = 0; m < 4; ++m)
#pragma unroll
                for (int n = 0; n < 4; ++n)
                    acc[m][n] = __builtin_amdgcn_mfma_f32_16x16x32_bf16(
                        af[m][kk], bfr[n][kk], acc[m][n], 0, 0, 0);
        __syncthreads();
    }

    const float* w2be = w2b + e*HID_;
#pragma unroll
    for (int n = 0; n < 4; ++n) {
        int col = n0 + wn*64 + n*16 + (lane & 15);
        float bias = w2be[col];
#pragma unroll
        for (int m = 0; m < 4; ++m) {
            int rb2 = t0 + wm*64 + m*16 + (lane >> 4)*4;
#pragma unroll
            for (int i = 0; i < 4; ++i) {
                int t = rb2 + i;
                if (t < ce) {
                    int p   = base + t;
                    float w = gwt[p];
                    atomicAdd(&out[(size_t)gtok[p]*HID_ + col], w * (acc[m][n][i] + bias));
                }
            }
        }
    }
}

// ---------------------------------------------------------------------------
extern "C" void kernel_launch(void* const* d_in, const int* in_sizes, int n_in,
                              void* d_out, int out_size, void* d_ws, size_t ws_size,
                              hipStream_t stream)
{
    const float* x   = (const float*)d_in[0];
    const float* rw  = (const float*)d_in[1];
    const float* rb  = (const float*)d_in[2];
    const float* w1  = (const float*)d_in[3];
    const float* w1b = (const float*)d_in[4];
    const float* w2  = (const float*)d_in[5];
    const float* w2b = (const float*)d_in[6];

    float* out      = (float*)d_out;
    float* topk_out = out + (size_t)M_ * HID_;

    char*  ws   = (char*)d_ws;
    int*   ids  = (int*)  (ws);
    float* wts  = (float*)(ws + 16384);
    int*   gtok = (int*)  (ws + 32768);
    float* gwt  = (float*)(ws + 49152);
    int*   cnt  = (int*)  (ws + 65536);
    int*   off  = (int*)  (ws + 65536 + 128);
    int*   fill = (int*)  (ws + 65536 + 256);
    int*   pos  = (int*)  (ws + 98304);

    const size_t MB = 1024*1024;
    __hip_bfloat16* xb    = (__hip_bfloat16*)(ws + 131072);            // 4 MB
    __hip_bfloat16* h     = (__hip_bfloat16*)(ws + 131072 + 4*MB);     // 16 MB
    float*          dpair = (float*)         (ws + 131072 + 20*MB);    // 16 MB
    __hip_bfloat16* w1bf  = (__hip_bfloat16*)(ws + 131072 + 36*MB);    // 64 MB
    __hip_bfloat16* w2bf  = (__hip_bfloat16*)(ws + 131072 + 100*MB);   // 32 MB
    const bool tier2 = (ws_size >= 131072 + 132*MB);

    hipMemsetAsync(cnt, 0, E_ * sizeof(int), stream);

    cvt_kernel<<<2048, 256, 0, stream>>>(x, xb, (M_*HID_)/4);
    router_kernel<<<M_, 64, 0, stream>>>(x, rw, rb, ids, wts, cnt, topk_out);
    offsets_kernel<<<1, 64, 0, stream>>>(cnt, off, fill);
    scatter_kernel<<<M_/256, 256, 0, stream>>>(ids, wts, fill, gtok, gwt, pos);

    if (tier2) {
        cvt_kernel<<<4096, 256, 0, stream>>>(w1, w1bf, (E_*2*FFN_*HID_)/4);
        cvt_kernel<<<4096, 256, 0, stream>>>(w2, w2bf, (E_*HID_*FFN_)/4);
        hipMemsetAsync(dpair, 0, (size_t)NP_ * HID_ * sizeof(float), stream);

        dim3 g1(FFN_/64, M_/128, E_);        // (32, 16, 8)
        gemm1_kernel<<<g1, 256, 0, stream>>>(xb, w1bf, w1b, gtok, cnt, off, h);

        dim3 g2(HID_/128, M_/128, 2*E_);     // (8, 16, 16) split-K=2
        gemm2_kernel<<<g2, 256, 0, stream>>>(h, w2bf, w2b, gwt, cnt, off, dpair);

        combine_kernel<<<(M_*HID_)/(256*4), 256, 0, stream>>>(dpair, pos, out);
    } else {
        hipMemsetAsync(out, 0, (size_t)M_ * HID_ * sizeof(float), stream);

        dim3 g1(FFN_/64, M_/128, E_);
        gemm1_rs_kernel<<<g1, 256, 0, stream>>>(xb, w1, w1b, gtok, cnt, off, h);

        dim3 g2(HID_/128, M_/128, E_);
        gemm2_rs_kernel<<<g2, 256, 0, stream>>>(h, w2, w2b, gtok, gwt, cnt, off, out);
    }
}

// Round 5
// 280.853 us; speedup vs baseline: 1.2844x; 1.1369x over previous
//
#include <hip/hip_runtime.h>
#include <hip/hip_bf16.h>
#include <math.h>

#define E_    8
#define HID_  1024
#define FFN_  2048
#define M_    2048     // B*S
#define NP_   (M_*2)   // total (token, expert) pairs

typedef __attribute__((ext_vector_type(8))) short bf16x8;
typedef __attribute__((ext_vector_type(4))) float f32x4;

typedef const __attribute__((address_space(1))) void GVOID;
typedef __attribute__((address_space(3))) void LVOID;

__device__ __forceinline__ short f2bf(float f) {
    union { __hip_bfloat16 b; short s; } u;
    u.b = __float2bfloat16(f);
    return u.s;
}

// ---------------------------------------------------------------------------
// fp32 -> bf16 elementwise (grid-stride, float4 in / short4 out)
// ---------------------------------------------------------------------------
__global__ __launch_bounds__(256) void cvt_kernel(
    const float* __restrict__ src, __hip_bfloat16* __restrict__ dst, int n4)
{
    int stride = gridDim.x * 256;
    for (int i = blockIdx.x * 256 + threadIdx.x; i < n4; i += stride) {
        float4 v = ((const float4*)src)[i];
        short4 o;
        o.x = f2bf(v.x); o.y = f2bf(v.y); o.z = f2bf(v.z); o.w = f2bf(v.w);
        ((short4*)dst)[i] = o;
    }
}

// ---------------------------------------------------------------------------
// Router v2: one wave per token. x row held in registers (4x float4/lane,
// lane-contiguous -> fully coalesced); per expert 4 float4 w-loads + 16 FMAs.
// ---------------------------------------------------------------------------
__global__ __launch_bounds__(64) void router_kernel(
    const float* __restrict__ x, const float* __restrict__ rw,
    const float* __restrict__ rb, int* __restrict__ ids,
    float* __restrict__ wts, int* __restrict__ cnt,
    float* __restrict__ topk_out)
{
    const int m    = blockIdx.x;
    const int lane = threadIdx.x;
    const float4* xm4 = (const float4*)(x + (size_t)m * HID_);

    float4 xv[4];
#pragma unroll
    for (int j = 0; j < 4; ++j) xv[j] = xm4[j*64 + lane];

    float lg[E_];
#pragma unroll
    for (int e = 0; e < E_; ++e) {
        const float4* we4 = (const float4*)(rw + e * HID_);
        float s = 0.f;
#pragma unroll
        for (int j = 0; j < 4; ++j) {
            float4 w = we4[j*64 + lane];
            s = fmaf(xv[j].x, w.x, s);
            s = fmaf(xv[j].y, w.y, s);
            s = fmaf(xv[j].z, w.z, s);
            s = fmaf(xv[j].w, w.w, s);
        }
        lg[e] = s;
    }
#pragma unroll
    for (int off = 32; off; off >>= 1)
#pragma unroll
        for (int e = 0; e < E_; ++e) lg[e] += __shfl_xor(lg[e], off);

    if (lane == 0) {
        float l2[E_], p[E_];
        float mx = -1e30f;
#pragma unroll
        for (int e = 0; e < E_; ++e) { l2[e] = lg[e] + rb[e]; mx = fmaxf(mx, l2[e]); }
        float sum = 0.f;
#pragma unroll
        for (int e = 0; e < E_; ++e) { p[e] = expf(l2[e] - mx); sum += p[e]; }
        float inv = 1.f / sum;
#pragma unroll
        for (int e = 0; e < E_; ++e) p[e] *= inv;

        int   i1 = -1, i2 = -1;
        float v1 = -1e30f, v2 = -1e30f;
#pragma unroll
        for (int e = 0; e < E_; ++e) {
            float pe = p[e];
            if (pe > v1)      { v2 = v1; i2 = i1; v1 = pe; i1 = e; }
            else if (pe > v2) { v2 = pe; i2 = e; }
        }
        ids[2*m]   = i1;  ids[2*m+1]   = i2;
        wts[2*m]   = v1;  wts[2*m+1]   = v2;
        topk_out[2*m]   = v1;
        topk_out[2*m+1] = v2;
        atomicAdd(&cnt[i1], 1);
        atomicAdd(&cnt[i2], 1);
    }
}

__global__ void offsets_kernel(const int* __restrict__ cnt,
                               int* __restrict__ off, int* __restrict__ fill)
{
    if (threadIdx.x == 0 && blockIdx.x == 0) {
        int acc = 0;
        for (int e = 0; e < E_; ++e) { off[e] = acc; fill[e] = acc; acc += cnt[e]; }
    }
}

__global__ __launch_bounds__(256) void scatter_kernel(
    const int* __restrict__ ids, const float* __restrict__ wts,
    int* __restrict__ fill, int* __restrict__ gtok, float* __restrict__ gwt,
    int* __restrict__ pos)
{
    int m = blockIdx.x * 256 + threadIdx.x;
    if (m >= M_) return;
#pragma unroll
    for (int s = 0; s < 2; ++s) {
        int e = ids[2*m + s];
        int p = atomicAdd(&fill[e], 1);
        gtok[p] = m;
        gwt[p]  = wts[2*m + s];
        pos[2*m + s] = p;
    }
}

// ===========================================================================
// TIER-2 GEMMs: bf16 weights, both operands via global_load_lds, BK=32,
// double-buffered, ONE barrier per K-step (T3 minimum 2-phase).
// LDS swizzle: 16B chunk p of row r holds global chunk p ^ ((r>>1)&3).
// ===========================================================================

// GEMM1: 128 gathered tokens x 64 h-cols. K = HID = 1024, 32 steps.
__global__ __launch_bounds__(256, 3) void gemm1_kernel(
    const __hip_bfloat16* __restrict__ xb, const __hip_bfloat16* __restrict__ w1bf,
    const float* __restrict__ w1b, const int* __restrict__ gtok,
    const int* __restrict__ cnt, const int* __restrict__ off,
    __hip_bfloat16* __restrict__ h)
{
    const int e  = blockIdx.z;
    const int ce = cnt[e];
    const int t0 = blockIdx.y * 128;
    if (t0 >= ce) return;
    const int n0   = blockIdx.x * 64;
    const int base = off[e];
    const __hip_bfloat16* w1e = w1bf + (size_t)e * (2*FFN_) * HID_;

    __shared__ __align__(16) __hip_bfloat16 As[2][128*32];
    __shared__ __align__(16) __hip_bfloat16 Bs[2][128*32];

    const int tid  = threadIdx.x;
    const int lane = tid & 63;
    const int wid  = tid >> 6;
    const int wm   = wid >> 1;
    const int wn   = wid & 1;

    const __hip_bfloat16 *asrc[2], *bsrc[2];
#pragma unroll
    for (int q = 0; q < 2; ++q) {
        int slot = q*256 + tid;
        int r = slot >> 2, p = slot & 3;
        int c = p ^ ((r >> 1) & 3);
        int rr  = min(t0 + r, ce - 1);
        asrc[q] = xb + (size_t)gtok[base + rr] * HID_ + c*8;
        int q2 = r >> 5, s = r & 31;
        int grow = (q2 & 1) ? (FFN_ + n0 + (q2>>1)*32 + s)
                            : (       n0 + (q2>>1)*32 + s);
        bsrc[q] = w1e + (size_t)grow * HID_ + c*8;
    }

    auto STAGE = [&](int b, int k0) {
#pragma unroll
        for (int q = 0; q < 2; ++q)
            __builtin_amdgcn_global_load_lds((GVOID*)(asrc[q] + k0),
                (LVOID*)(&As[b][(q*256 + wid*64)*8]), 16, 0, 0);
#pragma unroll
        for (int q = 0; q < 2; ++q)
            __builtin_amdgcn_global_load_lds((GVOID*)(bsrc[q] + k0),
                (LVOID*)(&Bs[b][(q*256 + wid*64)*8]), 16, 0, 0);
    };

    f32x4 acc[4][4];
#pragma unroll
    for (int m = 0; m < 4; ++m)
#pragma unroll
        for (int n = 0; n < 4; ++n) acc[m][n] = (f32x4){0.f,0.f,0.f,0.f};

    STAGE(0, 0);
    __syncthreads();

    const int NT = HID_/32;   // 32
    const int cf = lane >> 4;
    for (int t = 0; t < NT; ++t) {
        const int cur = t & 1, nxt = cur ^ 1;
        if (t + 1 < NT) STAGE(nxt, (t+1)*32);

        bf16x8 af[4], bfr[4];
#pragma unroll
        for (int m = 0; m < 4; ++m) {
            int r = wm*64 + m*16 + (lane & 15);
            int sw = cf ^ ((r >> 1) & 3);
            af[m] = *(bf16x8*)&As[cur][r*32 + sw*8];
        }
#pragma unroll
        for (int n = 0; n < 4; ++n) {
            int r = wn*64 + n*16 + (lane & 15);
            int sw = cf ^ ((r >> 1) & 3);
            bfr[n] = *(bf16x8*)&Bs[cur][r*32 + sw*8];
        }
        __builtin_amdgcn_s_setprio(1);
#pragma unroll
        for (int m = 0; m < 4; ++m)
#pragma unroll
            for (int n = 0; n < 4; ++n)
                acc[m][n] = __builtin_amdgcn_mfma_f32_16x16x32_bf16(
                    af[m], bfr[n], acc[m][n], 0, 0, 0);
        __builtin_amdgcn_s_setprio(0);
        __syncthreads();
    }

    // Epilogue: fused SiLU(gate)*up -> h (bf16)
    const float* w1be = w1b + e*2*FFN_;
#pragma unroll
    for (int n = 0; n < 2; ++n) {
        int col = n0 + wn*32 + n*16 + (lane & 15);
        float bg = w1be[col];
        float bu = w1be[FFN_ + col];
#pragma unroll
        for (int m = 0; m < 4; ++m) {
            int rb2 = t0 + wm*64 + m*16 + (lane >> 4)*4;
#pragma unroll
            for (int i = 0; i < 4; ++i) {
                int t = rb2 + i;
                if (t < ce) {
                    float g = acc[m][n][i]   + bg;
                    float u = acc[m][n+2][i] + bu;
                    float hv = (g / (1.f + __expf(-g))) * u;
                    h[(size_t)(base + t)*FFN_ + col] = __float2bfloat16(hv);
                }
            }
        }
    }
}

// GEMM2: 128 pairs x 128 hid cols, split-K=2 (z = e + 8*ks).
__global__ __launch_bounds__(256, 3) void gemm2_kernel(
    const __hip_bfloat16* __restrict__ h, const __hip_bfloat16* __restrict__ w2bf,
    const float* __restrict__ w2b, const float* __restrict__ gwt,
    const int* __restrict__ cnt, const int* __restrict__ off,
    float* __restrict__ dpair)
{
    const int e  = blockIdx.z & 7;
    const int ks = blockIdx.z >> 3;
    const int ce = cnt[e];
    const int t0 = blockIdx.y * 128;
    if (t0 >= ce) return;
    const int n0    = blockIdx.x * 128;
    const int base  = off[e];
    const int kbase = ks * (FFN_/2);
    const __hip_bfloat16* w2e = w2bf + (size_t)e * HID_ * FFN_;

    __shared__ __align__(16) __hip_bfloat16 As[2][128*32];
    __shared__ __align__(16) __hip_bfloat16 Bs[2][128*32];

    const int tid  = threadIdx.x;
    const int lane = tid & 63;
    const int wid  = tid >> 6;
    const int wm   = wid >> 1;
    const int wn   = wid & 1;

    const __hip_bfloat16 *asrc[2], *bsrc[2];
#pragma unroll
    for (int q = 0; q < 2; ++q) {
        int slot = q*256 + tid;
        int r = slot >> 2, p = slot & 3;
        int c = p ^ ((r >> 1) & 3);
        int rr = min(t0 + r, ce - 1);
        asrc[q] = h   + (size_t)(base + rr) * FFN_ + kbase + c*8;
        bsrc[q] = w2e + (size_t)(n0 + r)    * FFN_ + kbase + c*8;
    }

    auto STAGE = [&](int b, int k0) {
#pragma unroll
        for (int q = 0; q < 2; ++q)
            __builtin_amdgcn_global_load_lds((GVOID*)(asrc[q] + k0),
                (LVOID*)(&As[b][(q*256 + wid*64)*8]), 16, 0, 0);
#pragma unroll
        for (int q = 0; q < 2; ++q)
            __builtin_amdgcn_global_load_lds((GVOID*)(bsrc[q] + k0),
                (LVOID*)(&Bs[b][(q*256 + wid*64)*8]), 16, 0, 0);
    };

    f32x4 acc[4][4];
#pragma unroll
    for (int m = 0; m < 4; ++m)
#pragma unroll
        for (int n = 0; n < 4; ++n) acc[m][n] = (f32x4){0.f,0.f,0.f,0.f};

    STAGE(0, 0);
    __syncthreads();

    const int NT = (FFN_/2)/32;   // 32
    const int cf = lane >> 4;
    for (int t = 0; t < NT; ++t) {
        const int cur = t & 1, nxt = cur ^ 1;
        if (t + 1 < NT) STAGE(nxt, (t+1)*32);

        bf16x8 af[4], bfr[4];
#pragma unroll
        for (int m = 0; m < 4; ++m) {
            int r = wm*64 + m*16 + (lane & 15);
            int sw = cf ^ ((r >> 1) & 3);
            af[m] = *(bf16x8*)&As[cur][r*32 + sw*8];
        }
#pragma unroll
        for (int n = 0; n < 4; ++n) {
            int r = wn*64 + n*16 + (lane & 15);
            int sw = cf ^ ((r >> 1) & 3);
            bfr[n] = *(bf16x8*)&Bs[cur][r*32 + sw*8];
        }
        __builtin_amdgcn_s_setprio(1);
#pragma unroll
        for (int m = 0; m < 4; ++m)
#pragma unroll
            for (int n = 0; n < 4; ++n)
                acc[m][n] = __builtin_amdgcn_mfma_f32_16x16x32_bf16(
                    af[m], bfr[n], acc[m][n], 0, 0, 0);
        __builtin_amdgcn_s_setprio(0);
        __syncthreads();
    }

    const float* w2be = w2b + e*HID_;
#pragma unroll
    for (int n = 0; n < 4; ++n) {
        int col = n0 + wn*64 + n*16 + (lane & 15);
        float bias = (ks == 0) ? w2be[col] : 0.f;
#pragma unroll
        for (int m = 0; m < 4; ++m) {
            int rb2 = t0 + wm*64 + m*16 + (lane >> 4)*4;
#pragma unroll
            for (int i = 0; i < 4; ++i) {
                int t = rb2 + i;
                if (t < ce) {
                    int p   = base + t;
                    float w = gwt[p];
                    atomicAdd(&dpair[(size_t)p*HID_ + col], w * (acc[m][n][i] + bias));
                }
            }
        }
    }
}

// out[m][c] = dpair[pos[2m]][c] + dpair[pos[2m+1]][c]
__global__ __launch_bounds__(256) void combine_kernel(
    const float* __restrict__ dpair, const int* __restrict__ pos,
    float* __restrict__ out)
{
    int idx = blockIdx.x * 256 + threadIdx.x;
    int m   = idx >> 8;
    int c4  = (idx & 255) * 4;
    int p0 = pos[2*m], p1 = pos[2*m+1];
    float4 a = *(const float4*)(dpair + (size_t)p0*HID_ + c4);
    float4 b = *(const float4*)(dpair + (size_t)p1*HID_ + c4);
    float4 o = make_float4(a.x+b.x, a.y+b.y, a.z+b.z, a.w+b.w);
    *(float4*)(out + (size_t)m*HID_ + c4) = o;
}

// ===========================================================================
// FALLBACK (round-2 exact, proven) — used only if ws_size too small for tier2.
// ===========================================================================
__global__ __launch_bounds__(256) void gemm1_rs_kernel(
    const __hip_bfloat16* __restrict__ xb, const float* __restrict__ w1,
    const float* __restrict__ w1b, const int* __restrict__ gtok,
    const int* __restrict__ cnt, const int* __restrict__ off,
    __hip_bfloat16* __restrict__ h)
{
    const int e  = blockIdx.z;
    const int ce = cnt[e];
    const int t0 = blockIdx.y * 128;
    if (t0 >= ce) return;
    const int n0   = blockIdx.x * 64;
    const int base = off[e];
    const float* w1e = w1 + (size_t)e * (2*FFN_) * HID_;

    __shared__ __align__(16) __hip_bfloat16 As[128*64];
    __shared__ __align__(16) __hip_bfloat16 Bs[128*64];

    const int tid  = threadIdx.x;
    const int lane = tid & 63;
    const int wid  = tid >> 6;
    const int wm   = wid >> 1;
    const int wn   = wid & 1;

    const __hip_bfloat16* asrc[4];
#pragma unroll
    for (int q = 0; q < 4; ++q) {
        int slot = q*256 + tid;
        int r = slot >> 3, p = slot & 7;
        int rr  = min(t0 + r, ce - 1);
        int tok = gtok[base + rr];
        int c = p ^ (r & 7);
        asrc[q] = xb + (size_t)tok * HID_ + c*8;
    }

    const int brow = tid >> 1;
    const int hk   = tid & 1;
    const int q2 = brow >> 5, s = brow & 31;
    const int grow = (q2 & 1) ? (FFN_ + n0 + (q2>>1)*32 + s)
                              : (       n0 + (q2>>1)*32 + s);
    const float* bsrc = w1e + (size_t)grow * HID_ + hk*32;

    f32x4 acc[4][4];
#pragma unroll
    for (int m = 0; m < 4; ++m)
#pragma unroll
        for (int n = 0; n < 4; ++n) acc[m][n] = (f32x4){0.f,0.f,0.f,0.f};

    float4 breg[8];
#pragma unroll
    for (int j = 0; j < 8; ++j) breg[j] = *(const float4*)(bsrc + j*4);

    for (int k0 = 0; k0 < HID_; k0 += 64) {
#pragma unroll
        for (int q = 0; q < 4; ++q) {
            __builtin_amdgcn_global_load_lds(
                (GVOID*)(asrc[q] + k0),
                (LVOID*)(&As[(q*256 + wid*64)*8]), 16, 0, 0);
        }
#pragma unroll
        for (int cc = 0; cc < 4; ++cc) {
            union { bf16x8 v; short s8[8]; } u;
            const float* f0 = (const float*)&breg[2*cc];
#pragma unroll
            for (int j = 0; j < 8; ++j) u.s8[j] = f2bf(f0[j]);
            int c = hk*4 + cc, p = c ^ (brow & 7);
            *(bf16x8*)&Bs[brow*64 + p*8] = u.v;
        }
        __syncthreads();

        if (k0 + 64 < HID_) {
#pragma unroll
            for (int j = 0; j < 8; ++j) breg[j] = *(const float4*)(bsrc + (k0+64) + j*4);
        }

        bf16x8 af[4][2], bfr[4][2];
#pragma unroll
        for (int m = 0; m < 4; ++m)
#pragma unroll
            for (int kk = 0; kk < 2; ++kk) {
                int r = wm*64 + m*16 + (lane & 15);
                int c = kk*4 + (lane >> 4), p = c ^ (r & 7);
                af[m][kk] = *(bf16x8*)&As[r*64 + p*8];
            }
#pragma unroll
        for (int n = 0; n < 4; ++n)
#pragma unroll
            for (int kk = 0; kk < 2; ++kk) {
                int r = wn*64 + n*16 + (lane & 15);
                int c = kk*4 + (lane >> 4), p = c ^ (r & 7);
                bfr[n][kk] = *(bf16x8*)&Bs[r*64 + p*8];
            }
#pragma unroll
        for (int kk = 0; kk < 2; ++kk)
#pragma unroll
            for (int m = 0; m < 4; ++m)
#pragma unroll
                for (int n = 0; n < 4; ++n)
                    acc[m][n] = __builtin_amdgcn_mfma_f32_16x16x32_bf16(
                        af[m][kk], bfr[n][kk], acc[m][n], 0, 0, 0);
        __syncthreads();
    }

    const float* w1be = w1b + e*2*FFN_;
#pragma unroll
    for (int n = 0; n < 2; ++n) {
        int col = n0 + wn*32 + n*16 + (lane & 15);
        float bg = w1be[col];
        float bu = w1be[FFN_ + col];
#pragma unroll
        for (int m = 0; m < 4; ++m) {
            int rb2 = t0 + wm*64 + m*16 + (lane >> 4)*4;
#pragma unroll
            for (int i = 0; i < 4; ++i) {
                int t = rb2 + i;
                if (t < ce) {
                    float g = acc[m][n][i]   + bg;
                    float u = acc[m][n+2][i] + bu;
                    float hv = (g / (1.f + __expf(-g))) * u;
                    h[(size_t)(base + t)*FFN_ + col] = __float2bfloat16(hv);
                }
            }
        }
    }
}

__global__ __launch_bounds__(256) void gemm2_rs_kernel(
    const __hip_bfloat16* __restrict__ h, const float* __restrict__ w2,
    const float* __restrict__ w2b, const int* __restrict__ gtok,
    const float* __restrict__ gwt, const int* __restrict__ cnt,
    const int* __restrict__ off, float* __restrict__ out)
{
    const int e  = blockIdx.z;
    const int ce = cnt[e];
    const int t0 = blockIdx.y * 128;
    if (t0 >= ce) return;
    const int n0   = blockIdx.x * 128;
    const int base = off[e];
    const float* w2e = w2 + (size_t)e * HID_ * FFN_;

    __shared__ __align__(16) __hip_bfloat16 As[128*64];
    __shared__ __align__(16) __hip_bfloat16 Bs[128*64];

    const int tid  = threadIdx.x;
    const int lane = tid & 63;
    const int wid  = tid >> 6;
    const int wm   = wid >> 1;
    const int wn   = wid & 1;

    const __hip_bfloat16* asrc[4];
#pragma unroll
    for (int q = 0; q < 4; ++q) {
        int slot = q*256 + tid;
        int r = slot >> 3, p = slot & 7;
        int rr = min(t0 + r, ce - 1);
        int c = p ^ (r & 7);
        asrc[q] = h + (size_t)(base + rr) * FFN_ + c*8;
    }

    const int brow = tid >> 1;
    const int hk   = tid & 1;
    const float* bsrc = w2e + (size_t)(n0 + brow) * FFN_ + hk*32;

    f32x4 acc[4][4];
#pragma unroll
    for (int m = 0; m < 4; ++m)
#pragma unroll
        for (int n = 0; n < 4; ++n) acc[m][n] = (f32x4){0.f,0.f,0.f,0.f};

    float4 breg[8];
#pragma unroll
    for (int j = 0; j < 8; ++j) breg[j] = *(const float4*)(bsrc + j*4);

    for (int k0 = 0; k0 < FFN_; k0 += 64) {
#pragma unroll
        for (int q = 0; q < 4; ++q) {
            __builtin_amdgcn_global_load_lds(
                (GVOID*)(asrc[q] + k0),
                (LVOID*)(&As[(q*256 + wid*64)*8]), 16, 0, 0);
        }
#pragma unroll
        for (int cc = 0; cc < 4; ++cc) {
            union { bf16x8 v; short s8[8]; } u;
            const float* f0 = (const float*)&breg[2*cc];
#pragma unroll
            for (int j = 0; j < 8; ++j) u.s8[j] = f2bf(f0[j]);
            int c = hk*4 + cc, p = c ^ (brow & 7);
            *(bf16x8*)&Bs[brow*64 + p*8] = u.v;
        }
        __syncthreads();

        if (k0 + 64 < FFN_) {
#pragma unroll
            for (int j = 0; j < 8; ++j) breg[j] = *(const float4*)(bsrc + (k0+64) + j*4);
        }

        bf16x8 af[4][2], bfr[4][2];
#pragma unroll
        for (int m = 0; m < 4; ++m)
#pragma unroll
            for (int kk = 0; kk < 2; ++kk) {
                int r = wm*64 + m*16 + (lane & 15);
                int c = kk*4 + (lane >> 4), p = c ^ (r & 7);
                af[m][kk] = *(bf16x8*)&As[r*64 + p*8];
            }
#pragma unroll
        for (int n = 0; n < 4; ++n)
#pragma unroll
            for (int kk = 0; kk < 2; ++kk) {
                int r = wn*64 + n*16 + (lane & 15);
                int c = kk*4 + (lane >> 4), p = c ^ (r & 7);
                bfr[n][kk] = *(bf16x8*)&Bs[r*64 + p*8];
            }
#pragma unroll
        for (int kk = 0; kk < 2; ++kk)
#pragma unroll
            for (int m = 0; m < 4; ++m)
#pragma unroll
                for (int n = 0; n < 4; ++n)
                    acc[m][n] = __builtin_amdgcn_mfma_f32_16x16x32_bf16(
                        af[m][kk], bfr[n][kk], acc[m][n], 0, 0, 0);
        __syncthreads();
    }

    const float* w2be = w2b + e*HID_;
#pragma unroll
    for (int n = 0; n < 4; ++n) {
        int col = n0 + wn*64 + n*16 + (lane & 15);
        float bias = w2be[col];
#pragma unroll
        for (int m = 0; m < 4; ++m) {
            int rb2 = t0 + wm*64 + m*16 + (lane >> 4)*4;
#pragma unroll
            for (int i = 0; i < 4; ++i) {
                int t = rb2 + i;
                if (t < ce) {
                    int p   = base + t;
                    float w = gwt[p];
                    atomicAdd(&out[(size_t)gtok[p]*HID_ + col], w * (acc[m][n][i] + bias));
                }
            }
        }
    }
}

// ---------------------------------------------------------------------------
extern "C" void kernel_launch(void* const* d_in, const int* in_sizes, int n_in,
                              void* d_out, int out_size, void* d_ws, size_t ws_size,
                              hipStream_t stream)
{
    const float* x   = (const float*)d_in[0];
    const float* rw  = (const float*)d_in[1];
    const float* rb  = (const float*)d_in[2];
    const float* w1  = (const float*)d_in[3];
    const float* w1b = (const float*)d_in[4];
    const float* w2  = (const float*)d_in[5];
    const float* w2b = (const float*)d_in[6];

    float* out      = (float*)d_out;
    float* topk_out = out + (size_t)M_ * HID_;

    char*  ws   = (char*)d_ws;
    int*   ids  = (int*)  (ws);
    float* wts  = (float*)(ws + 16384);
    int*   gtok = (int*)  (ws + 32768);
    float* gwt  = (float*)(ws + 49152);
    int*   cnt  = (int*)  (ws + 65536);
    int*   off  = (int*)  (ws + 65536 + 128);
    int*   fill = (int*)  (ws + 65536 + 256);
    int*   pos  = (int*)  (ws + 98304);

    const size_t MB = 1024*1024;
    __hip_bfloat16* xb    = (__hip_bfloat16*)(ws + 131072);            // 4 MB
    __hip_bfloat16* h     = (__hip_bfloat16*)(ws + 131072 + 4*MB);     // 16 MB
    float*          dpair = (float*)         (ws + 131072 + 20*MB);    // 16 MB
    __hip_bfloat16* w1bf  = (__hip_bfloat16*)(ws + 131072 + 36*MB);    // 64 MB
    __hip_bfloat16* w2bf  = (__hip_bfloat16*)(ws + 131072 + 100*MB);   // 32 MB
    const bool tier2 = (ws_size >= 131072 + 132*MB);

    hipMemsetAsync(cnt, 0, E_ * sizeof(int), stream);

    cvt_kernel<<<2048, 256, 0, stream>>>(x, xb, (M_*HID_)/4);
    router_kernel<<<M_, 64, 0, stream>>>(x, rw, rb, ids, wts, cnt, topk_out);
    offsets_kernel<<<1, 64, 0, stream>>>(cnt, off, fill);
    scatter_kernel<<<M_/256, 256, 0, stream>>>(ids, wts, fill, gtok, gwt, pos);

    if (tier2) {
        cvt_kernel<<<4096, 256, 0, stream>>>(w1, w1bf, (E_*2*FFN_*HID_)/4);
        cvt_kernel<<<4096, 256, 0, stream>>>(w2, w2bf, (E_*HID_*FFN_)/4);
        hipMemsetAsync(dpair, 0, (size_t)NP_ * HID_ * sizeof(float), stream);

        dim3 g1(FFN_/64, M_/128, E_);        // (32, 16, 8)
        gemm1_kernel<<<g1, 256, 0, stream>>>(xb, w1bf, w1b, gtok, cnt, off, h);

        dim3 g2(HID_/128, M_/128, 2*E_);     // (8, 16, 16) split-K=2
        gemm2_kernel<<<g2, 256, 0, stream>>>(h, w2bf, w2b, gwt, cnt, off, dpair);

        combine_kernel<<<(M_*HID_)/(256*4), 256, 0, stream>>>(dpair, pos, out);
    } else {
        hipMemsetAsync(out, 0, (size_t)M_ * HID_ * sizeof(float), stream);

        dim3 g1(FFN_/64, M_/128, E_);
        gemm1_rs_kernel<<<g1, 256, 0, stream>>>(xb, w1, w1b, gtok, cnt, off, h);

        dim3 g2(HID_/128, M_/128, E_);
        gemm2_rs_kernel<<<g2, 256, 0, stream>>>(h, w2, w2b, gtok, gwt, cnt, off, out);
    }
}

// Round 6
// 252.174 us; speedup vs baseline: 1.4305x; 1.1137x over previous
//
#include <hip/hip_runtime.h>
#include <hip/hip_bf16.h>
#include <math.h>

#define E_    8
#define HID_  1024
#define FFN_  2048
#define M_    2048     // B*S
#define NP_   (M_*2)   // total (token, expert) pairs

typedef __attribute__((ext_vector_type(8))) short bf16x8;
typedef __attribute__((ext_vector_type(4))) float f32x4;

typedef const __attribute__((address_space(1))) void GVOID;
typedef __attribute__((address_space(3))) void LVOID;

#define VMCNT4 asm volatile("s_waitcnt vmcnt(4)" ::: "memory")
#define VMCNT0 asm volatile("s_waitcnt vmcnt(0)" ::: "memory")

__device__ __forceinline__ short f2bf(float f) {
    union { __hip_bfloat16 b; short s; } u;
    u.b = __float2bfloat16(f);
    return u.s;
}

// ---------------------------------------------------------------------------
// fp32 -> bf16 elementwise (grid-stride, float4 in / short4 out)
// ---------------------------------------------------------------------------
__global__ __launch_bounds__(256) void cvt_kernel(
    const float* __restrict__ src, __hip_bfloat16* __restrict__ dst, int n4)
{
    int stride = gridDim.x * 256;
    for (int i = blockIdx.x * 256 + threadIdx.x; i < n4; i += stride) {
        float4 v = ((const float4*)src)[i];
        short4 o;
        o.x = f2bf(v.x); o.y = f2bf(v.y); o.z = f2bf(v.z); o.w = f2bf(v.w);
        ((short4*)dst)[i] = o;
    }
}

// ---------------------------------------------------------------------------
// Router v2 (proven): x row in registers, coalesced float4 loads.
// ---------------------------------------------------------------------------
__global__ __launch_bounds__(64) void router_kernel(
    const float* __restrict__ x, const float* __restrict__ rw,
    const float* __restrict__ rb, int* __restrict__ ids,
    float* __restrict__ wts, int* __restrict__ cnt,
    float* __restrict__ topk_out)
{
    const int m    = blockIdx.x;
    const int lane = threadIdx.x;
    const float4* xm4 = (const float4*)(x + (size_t)m * HID_);

    float4 xv[4];
#pragma unroll
    for (int j = 0; j < 4; ++j) xv[j] = xm4[j*64 + lane];

    float lg[E_];
#pragma unroll
    for (int e = 0; e < E_; ++e) {
        const float4* we4 = (const float4*)(rw + e * HID_);
        float s = 0.f;
#pragma unroll
        for (int j = 0; j < 4; ++j) {
            float4 w = we4[j*64 + lane];
            s = fmaf(xv[j].x, w.x, s);
            s = fmaf(xv[j].y, w.y, s);
            s = fmaf(xv[j].z, w.z, s);
            s = fmaf(xv[j].w, w.w, s);
        }
        lg[e] = s;
    }
#pragma unroll
    for (int off = 32; off; off >>= 1)
#pragma unroll
        for (int e = 0; e < E_; ++e) lg[e] += __shfl_xor(lg[e], off);

    if (lane == 0) {
        float l2[E_], p[E_];
        float mx = -1e30f;
#pragma unroll
        for (int e = 0; e < E_; ++e) { l2[e] = lg[e] + rb[e]; mx = fmaxf(mx, l2[e]); }
        float sum = 0.f;
#pragma unroll
        for (int e = 0; e < E_; ++e) { p[e] = expf(l2[e] - mx); sum += p[e]; }
        float inv = 1.f / sum;
#pragma unroll
        for (int e = 0; e < E_; ++e) p[e] *= inv;

        int   i1 = -1, i2 = -1;
        float v1 = -1e30f, v2 = -1e30f;
#pragma unroll
        for (int e = 0; e < E_; ++e) {
            float pe = p[e];
            if (pe > v1)      { v2 = v1; i2 = i1; v1 = pe; i1 = e; }
            else if (pe > v2) { v2 = pe; i2 = e; }
        }
        ids[2*m]   = i1;  ids[2*m+1]   = i2;
        wts[2*m]   = v1;  wts[2*m+1]   = v2;
        topk_out[2*m]   = v1;
        topk_out[2*m+1] = v2;
        atomicAdd(&cnt[i1], 1);
        atomicAdd(&cnt[i2], 1);
    }
}

__global__ void offsets_kernel(const int* __restrict__ cnt,
                               int* __restrict__ off, int* __restrict__ fill)
{
    if (threadIdx.x == 0 && blockIdx.x == 0) {
        int acc = 0;
        for (int e = 0; e < E_; ++e) { off[e] = acc; fill[e] = acc; acc += cnt[e]; }
    }
}

__global__ __launch_bounds__(256) void scatter_kernel(
    const int* __restrict__ ids, const float* __restrict__ wts,
    int* __restrict__ fill, int* __restrict__ gtok, float* __restrict__ gwt,
    int* __restrict__ pos)
{
    int m = blockIdx.x * 256 + threadIdx.x;
    if (m >= M_) return;
#pragma unroll
    for (int s = 0; s < 2; ++s) {
        int e = ids[2*m + s];
        int p = atomicAdd(&fill[e], 1);
        gtok[p] = m;
        gwt[p]  = wts[2*m + s];
        pos[2*m + s] = p;
    }
}

// ===========================================================================
// TIER-2 GEMMs: bf16 weights, both operands via global_load_lds, BK=32,
// TRIPLE-buffered with depth-2 prefetch + counted vmcnt(4) at barriers.
// LDS swizzle: 16B chunk p of row r holds global chunk p ^ ((r>>1)&3).
// STAGE issues exactly 4 global_load_lds per thread -> vmcnt(4) leaves only
// the newest tile's loads in flight.
// ===========================================================================

// GEMM1: 128 gathered tokens x 64 h-cols. K = HID = 1024, NT = 32 steps.
__global__ __launch_bounds__(256, 3) void gemm1_kernel(
    const __hip_bfloat16* __restrict__ xb, const __hip_bfloat16* __restrict__ w1bf,
    const float* __restrict__ w1b, const int* __restrict__ gtok,
    const int* __restrict__ cnt, const int* __restrict__ off,
    __hip_bfloat16* __restrict__ h)
{
    const int e  = blockIdx.z;
    const int ce = cnt[e];
    const int t0 = blockIdx.y * 128;
    if (t0 >= ce) return;
    const int n0   = blockIdx.x * 64;
    const int base = off[e];
    const __hip_bfloat16* w1e = w1bf + (size_t)e * (2*FFN_) * HID_;

    __shared__ __align__(16) __hip_bfloat16 As[3][128*32];
    __shared__ __align__(16) __hip_bfloat16 Bs[3][128*32];

    const int tid  = threadIdx.x;
    const int lane = tid & 63;
    const int wid  = tid >> 6;
    const int wm   = wid >> 1;
    const int wn   = wid & 1;

    const __hip_bfloat16 *asrc[2], *bsrc[2];
#pragma unroll
    for (int q = 0; q < 2; ++q) {
        int slot = q*256 + tid;
        int r = slot >> 2, p = slot & 3;
        int c = p ^ ((r >> 1) & 3);
        int rr  = min(t0 + r, ce - 1);
        asrc[q] = xb + (size_t)gtok[base + rr] * HID_ + c*8;
        int q2 = r >> 5, s = r & 31;
        int grow = (q2 & 1) ? (FFN_ + n0 + (q2>>1)*32 + s)
                            : (       n0 + (q2>>1)*32 + s);
        bsrc[q] = w1e + (size_t)grow * HID_ + c*8;
    }

    auto STAGE = [&](int b, int k0) {
#pragma unroll
        for (int q = 0; q < 2; ++q)
            __builtin_amdgcn_global_load_lds((GVOID*)(asrc[q] + k0),
                (LVOID*)(&As[b][(q*256 + wid*64)*8]), 16, 0, 0);
#pragma unroll
        for (int q = 0; q < 2; ++q)
            __builtin_amdgcn_global_load_lds((GVOID*)(bsrc[q] + k0),
                (LVOID*)(&Bs[b][(q*256 + wid*64)*8]), 16, 0, 0);
    };

    f32x4 acc[4][4];
#pragma unroll
    for (int m = 0; m < 4; ++m)
#pragma unroll
        for (int n = 0; n < 4; ++n) acc[m][n] = (f32x4){0.f,0.f,0.f,0.f};

    const int cf = lane >> 4;
    auto COMPUTE = [&](int cb) {
        bf16x8 af[4], bfr[4];
#pragma unroll
        for (int m = 0; m < 4; ++m) {
            int r = wm*64 + m*16 + (lane & 15);
            int sw = cf ^ ((r >> 1) & 3);
            af[m] = *(bf16x8*)&As[cb][r*32 + sw*8];
        }
#pragma unroll
        for (int n = 0; n < 4; ++n) {
            int r = wn*64 + n*16 + (lane & 15);
            int sw = cf ^ ((r >> 1) & 3);
            bfr[n] = *(bf16x8*)&Bs[cb][r*32 + sw*8];
        }
        __builtin_amdgcn_s_setprio(1);
#pragma unroll
        for (int m = 0; m < 4; ++m)
#pragma unroll
            for (int n = 0; n < 4; ++n)
                acc[m][n] = __builtin_amdgcn_mfma_f32_16x16x32_bf16(
                    af[m], bfr[n], acc[m][n], 0, 0, 0);
        __builtin_amdgcn_s_setprio(0);
    };

    const int NT = HID_/32;   // 32
    // prologue: tiles 0,1 staged; wait own tile-0 loads; barrier => buf0 ready
    STAGE(0, 0);
    STAGE(1, 32);
    VMCNT4;
    __builtin_amdgcn_s_barrier();

    int cb = 0;
    for (int t = 0; t < NT-2; ++t) {
        int sb = cb + 2; if (sb >= 3) sb -= 3;
        STAGE(sb, (t+2)*32);
        COMPUTE(cb);
        VMCNT4;                         // tile t+1 landed; t+2 stays in flight
        __builtin_amdgcn_s_barrier();
        if (++cb == 3) cb = 0;
    }
    COMPUTE(cb);                        // t = NT-2
    VMCNT0;
    __builtin_amdgcn_s_barrier();
    if (++cb == 3) cb = 0;
    COMPUTE(cb);                        // t = NT-1

    // Epilogue: fused SiLU(gate)*up -> h (bf16)
    const float* w1be = w1b + e*2*FFN_;
#pragma unroll
    for (int n = 0; n < 2; ++n) {
        int col = n0 + wn*32 + n*16 + (lane & 15);
        float bg = w1be[col];
        float bu = w1be[FFN_ + col];
#pragma unroll
        for (int m = 0; m < 4; ++m) {
            int rb2 = t0 + wm*64 + m*16 + (lane >> 4)*4;
#pragma unroll
            for (int i = 0; i < 4; ++i) {
                int t = rb2 + i;
                if (t < ce) {
                    float g = acc[m][n][i]   + bg;
                    float u = acc[m][n+2][i] + bu;
                    float hv = (g / (1.f + __expf(-g))) * u;
                    h[(size_t)(base + t)*FFN_ + col] = __float2bfloat16(hv);
                }
            }
        }
    }
}

// GEMM2: 128 pairs x 128 hid cols, split-K=2 (z = e + 8*ks). Plain stores
// into dpair[ks] (no init, no atomics); combine sums 4 slices.
__global__ __launch_bounds__(256, 3) void gemm2_kernel(
    const __hip_bfloat16* __restrict__ h, const __hip_bfloat16* __restrict__ w2bf,
    const float* __restrict__ w2b, const float* __restrict__ gwt,
    const int* __restrict__ cnt, const int* __restrict__ off,
    float* __restrict__ dpair)
{
    const int e  = blockIdx.z & 7;
    const int ks = blockIdx.z >> 3;
    const int ce = cnt[e];
    const int t0 = blockIdx.y * 128;
    if (t0 >= ce) return;
    const int n0    = blockIdx.x * 128;
    const int base  = off[e];
    const int kbase = ks * (FFN_/2);
    const __hip_bfloat16* w2e = w2bf + (size_t)e * HID_ * FFN_;

    __shared__ __align__(16) __hip_bfloat16 As[3][128*32];
    __shared__ __align__(16) __hip_bfloat16 Bs[3][128*32];

    const int tid  = threadIdx.x;
    const int lane = tid & 63;
    const int wid  = tid >> 6;
    const int wm   = wid >> 1;
    const int wn   = wid & 1;

    const __hip_bfloat16 *asrc[2], *bsrc[2];
#pragma unroll
    for (int q = 0; q < 2; ++q) {
        int slot = q*256 + tid;
        int r = slot >> 2, p = slot & 3;
        int c = p ^ ((r >> 1) & 3);
        int rr = min(t0 + r, ce - 1);
        asrc[q] = h   + (size_t)(base + rr) * FFN_ + kbase + c*8;
        bsrc[q] = w2e + (size_t)(n0 + r)    * FFN_ + kbase + c*8;
    }

    auto STAGE = [&](int b, int k0) {
#pragma unroll
        for (int q = 0; q < 2; ++q)
            __builtin_amdgcn_global_load_lds((GVOID*)(asrc[q] + k0),
                (LVOID*)(&As[b][(q*256 + wid*64)*8]), 16, 0, 0);
#pragma unroll
        for (int q = 0; q < 2; ++q)
            __builtin_amdgcn_global_load_lds((GVOID*)(bsrc[q] + k0),
                (LVOID*)(&Bs[b][(q*256 + wid*64)*8]), 16, 0, 0);
    };

    f32x4 acc[4][4];
#pragma unroll
    for (int m = 0; m < 4; ++m)
#pragma unroll
        for (int n = 0; n < 4; ++n) acc[m][n] = (f32x4){0.f,0.f,0.f,0.f};

    const int cf = lane >> 4;
    auto COMPUTE = [&](int cb) {
        bf16x8 af[4], bfr[4];
#pragma unroll
        for (int m = 0; m < 4; ++m) {
            int r = wm*64 + m*16 + (lane & 15);
            int sw = cf ^ ((r >> 1) & 3);
            af[m] = *(bf16x8*)&As[cb][r*32 + sw*8];
        }
#pragma unroll
        for (int n = 0; n < 4; ++n) {
            int r = wn*64 + n*16 + (lane & 15);
            int sw = cf ^ ((r >> 1) & 3);
            bfr[n] = *(bf16x8*)&Bs[cb][r*32 + sw*8];
        }
        __builtin_amdgcn_s_setprio(1);
#pragma unroll
        for (int m = 0; m < 4; ++m)
#pragma unroll
            for (int n = 0; n < 4; ++n)
                acc[m][n] = __builtin_amdgcn_mfma_f32_16x16x32_bf16(
                    af[m], bfr[n], acc[m][n], 0, 0, 0);
        __builtin_amdgcn_s_setprio(0);
    };

    const int NT = (FFN_/2)/32;   // 32
    STAGE(0, 0);
    STAGE(1, 32);
    VMCNT4;
    __builtin_amdgcn_s_barrier();

    int cb = 0;
    for (int t = 0; t < NT-2; ++t) {
        int sb = cb + 2; if (sb >= 3) sb -= 3;
        STAGE(sb, (t+2)*32);
        COMPUTE(cb);
        VMCNT4;
        __builtin_amdgcn_s_barrier();
        if (++cb == 3) cb = 0;
    }
    COMPUTE(cb);
    VMCNT0;
    __builtin_amdgcn_s_barrier();
    if (++cb == 3) cb = 0;
    COMPUTE(cb);

    const float* w2be = w2b + e*HID_;
    float* dpk = dpair + (size_t)ks * NP_ * HID_;
#pragma unroll
    for (int n = 0; n < 4; ++n) {
        int col = n0 + wn*64 + n*16 + (lane & 15);
        float bias = (ks == 0) ? w2be[col] : 0.f;
#pragma unroll
        for (int m = 0; m < 4; ++m) {
            int rb2 = t0 + wm*64 + m*16 + (lane >> 4)*4;
#pragma unroll
            for (int i = 0; i < 4; ++i) {
                int t = rb2 + i;
                if (t < ce) {
                    int p   = base + t;
                    float w = gwt[p];
                    dpk[(size_t)p*HID_ + col] = w * (acc[m][n][i] + bias);
                }
            }
        }
    }
}

// out[m][c] = d0[p0][c]+d1[p0][c]+d0[p1][c]+d1[p1][c]   (fixed order)
__global__ __launch_bounds__(256) void combine_kernel(
    const float* __restrict__ dpair, const int* __restrict__ pos,
    float* __restrict__ out)
{
    int idx = blockIdx.x * 256 + threadIdx.x;
    int m   = idx >> 8;
    int c4  = (idx & 255) * 4;
    int p0 = pos[2*m], p1 = pos[2*m+1];
    const float* d0 = dpair;
    const float* d1 = dpair + (size_t)NP_ * HID_;
    float4 a0 = *(const float4*)(d0 + (size_t)p0*HID_ + c4);
    float4 a1 = *(const float4*)(d1 + (size_t)p0*HID_ + c4);
    float4 b0 = *(const float4*)(d0 + (size_t)p1*HID_ + c4);
    float4 b1 = *(const float4*)(d1 + (size_t)p1*HID_ + c4);
    float4 o = make_float4((a0.x+a1.x)+(b0.x+b1.x), (a0.y+a1.y)+(b0.y+b1.y),
                           (a0.z+a1.z)+(b0.z+b1.z), (a0.w+a1.w)+(b0.w+b1.w));
    *(float4*)(out + (size_t)m*HID_ + c4) = o;
}

// ===========================================================================
// FALLBACK (round-2 exact, proven) — only if ws_size too small for tier2.
// ===========================================================================
__global__ __launch_bounds__(256) void gemm1_rs_kernel(
    const __hip_bfloat16* __restrict__ xb, const float* __restrict__ w1,
    const float* __restrict__ w1b, const int* __restrict__ gtok,
    const int* __restrict__ cnt, const int* __restrict__ off,
    __hip_bfloat16* __restrict__ h)
{
    const int e  = blockIdx.z;
    const int ce = cnt[e];
    const int t0 = blockIdx.y * 128;
    if (t0 >= ce) return;
    const int n0   = blockIdx.x * 64;
    const int base = off[e];
    const float* w1e = w1 + (size_t)e * (2*FFN_) * HID_;

    __shared__ __align__(16) __hip_bfloat16 As[128*64];
    __shared__ __align__(16) __hip_bfloat16 Bs[128*64];

    const int tid  = threadIdx.x;
    const int lane = tid & 63;
    const int wid  = tid >> 6;
    const int wm   = wid >> 1;
    const int wn   = wid & 1;

    const __hip_bfloat16* asrc[4];
#pragma unroll
    for (int q = 0; q < 4; ++q) {
        int slot = q*256 + tid;
        int r = slot >> 3, p = slot & 7;
        int rr  = min(t0 + r, ce - 1);
        int tok = gtok[base + rr];
        int c = p ^ (r & 7);
        asrc[q] = xb + (size_t)tok * HID_ + c*8;
    }

    const int brow = tid >> 1;
    const int hk   = tid & 1;
    const int q2 = brow >> 5, s = brow & 31;
    const int grow = (q2 & 1) ? (FFN_ + n0 + (q2>>1)*32 + s)
                              : (       n0 + (q2>>1)*32 + s);
    const float* bsrc = w1e + (size_t)grow * HID_ + hk*32;

    f32x4 acc[4][4];
#pragma unroll
    for (int m = 0; m < 4; ++m)
#pragma unroll
        for (int n = 0; n < 4; ++n) acc[m][n] = (f32x4){0.f,0.f,0.f,0.f};

    float4 breg[8];
#pragma unroll
    for (int j = 0; j < 8; ++j) breg[j] = *(const float4*)(bsrc + j*4);

    for (int k0 = 0; k0 < HID_; k0 += 64) {
#pragma unroll
        for (int q = 0; q < 4; ++q) {
            __builtin_amdgcn_global_load_lds(
                (GVOID*)(asrc[q] + k0),
                (LVOID*)(&As[(q*256 + wid*64)*8]), 16, 0, 0);
        }
#pragma unroll
        for (int cc = 0; cc < 4; ++cc) {
            union { bf16x8 v; short s8[8]; } u;
            const float* f0 = (const float*)&breg[2*cc];
#pragma unroll
            for (int j = 0; j < 8; ++j) u.s8[j] = f2bf(f0[j]);
            int c = hk*4 + cc, p = c ^ (brow & 7);
            *(bf16x8*)&Bs[brow*64 + p*8] = u.v;
        }
        __syncthreads();

        if (k0 + 64 < HID_) {
#pragma unroll
            for (int j = 0; j < 8; ++j) breg[j] = *(const float4*)(bsrc + (k0+64) + j*4);
        }

        bf16x8 af[4][2], bfr[4][2];
#pragma unroll
        for (int m = 0; m < 4; ++m)
#pragma unroll
            for (int kk = 0; kk < 2; ++kk) {
                int r = wm*64 + m*16 + (lane & 15);
                int c = kk*4 + (lane >> 4), p = c ^ (r & 7);
                af[m][kk] = *(bf16x8*)&As[r*64 + p*8];
            }
#pragma unroll
        for (int n = 0; n < 4; ++n)
#pragma unroll
            for (int kk = 0; kk < 2; ++kk) {
                int r = wn*64 + n*16 + (lane & 15);
                int c = kk*4 + (lane >> 4), p = c ^ (r & 7);
                bfr[n][kk] = *(bf16x8*)&Bs[r*64 + p*8];
            }
#pragma unroll
        for (int kk = 0; kk < 2; ++kk)
#pragma unroll
            for (int m = 0; m < 4; ++m)
#pragma unroll
                for (int n = 0; n < 4; ++n)
                    acc[m][n] = __builtin_amdgcn_mfma_f32_16x16x32_bf16(
                        af[m][kk], bfr[n][kk], acc[m][n], 0, 0, 0);
        __syncthreads();
    }

    const float* w1be = w1b + e*2*FFN_;
#pragma unroll
    for (int n = 0; n < 2; ++n) {
        int col = n0 + wn*32 + n*16 + (lane & 15);
        float bg = w1be[col];
        float bu = w1be[FFN_ + col];
#pragma unroll
        for (int m = 0; m < 4; ++m) {
            int rb2 = t0 + wm*64 + m*16 + (lane >> 4)*4;
#pragma unroll
            for (int i = 0; i < 4; ++i) {
                int t = rb2 + i;
                if (t < ce) {
                    float g = acc[m][n][i]   + bg;
                    float u = acc[m][n+2][i] + bu;
                    float hv = (g / (1.f + __expf(-g))) * u;
                    h[(size_t)(base + t)*FFN_ + col] = __float2bfloat16(hv);
                }
            }
        }
    }
}

__global__ __launch_bounds__(256) void gemm2_rs_kernel(
    const __hip_bfloat16* __restrict__ h, const float* __restrict__ w2,
    const float* __restrict__ w2b, const int* __restrict__ gtok,
    const float* __restrict__ gwt, const int* __restrict__ cnt,
    const int* __restrict__ off, float* __restrict__ out)
{
    const int e  = blockIdx.z;
    const int ce = cnt[e];
    const int t0 = blockIdx.y * 128;
    if (t0 >= ce) return;
    const int n0   = blockIdx.x * 128;
    const int base = off[e];
    const float* w2e = w2 + (size_t)e * HID_ * FFN_;

    __shared__ __align__(16) __hip_bfloat16 As[128*64];
    __shared__ __align__(16) __hip_bfloat16 Bs[128*64];

    const int tid  = threadIdx.x;
    const int lane = tid & 63;
    const int wid  = tid >> 6;
    const int wm   = wid >> 1;
    const int wn   = wid & 1;

    const __hip_bfloat16* asrc[4];
#pragma unroll
    for (int q = 0; q < 4; ++q) {
        int slot = q*256 + tid;
        int r = slot >> 3, p = slot & 7;
        int rr = min(t0 + r, ce - 1);
        int c = p ^ (r & 7);
        asrc[q] = h + (size_t)(base + rr) * FFN_ + c*8;
    }

    const int brow = tid >> 1;
    const int hk   = tid & 1;
    const float* bsrc = w2e + (size_t)(n0 + brow) * FFN_ + hk*32;

    f32x4 acc[4][4];
#pragma unroll
    for (int m = 0; m < 4; ++m)
#pragma unroll
        for (int n = 0; n < 4; ++n) acc[m][n] = (f32x4){0.f,0.f,0.f,0.f};

    float4 breg[8];
#pragma unroll
    for (int j = 0; j < 8; ++j) breg[j] = *(const float4*)(bsrc + j*4);

    for (int k0 = 0; k0 < FFN_; k0 += 64) {
#pragma unroll
        for (int q = 0; q < 4; ++q) {
            __builtin_amdgcn_global_load_lds(
                (GVOID*)(asrc[q] + k0),
                (LVOID*)(&As[(q*256 + wid*64)*8]), 16, 0, 0);
        }
#pragma unroll
        for (int cc = 0; cc < 4; ++cc) {
            union { bf16x8 v; short s8[8]; } u;
            const float* f0 = (const float*)&breg[2*cc];
#pragma unroll
            for (int j = 0; j < 8; ++j) u.s8[j] = f2bf(f0[j]);
            int c = hk*4 + cc, p = c ^ (brow & 7);
            *(bf16x8*)&Bs[brow*64 + p*8] = u.v;
        }
        __syncthreads();

        if (k0 + 64 < FFN_) {
#pragma unroll
            for (int j = 0; j < 8; ++j) breg[j] = *(const float4*)(bsrc + (k0+64) + j*4);
        }

        bf16x8 af[4][2], bfr[4][2];
#pragma unroll
        for (int m = 0; m < 4; ++m)
#pragma unroll
            for (int kk = 0; kk < 2; ++kk) {
                int r = wm*64 + m*16 + (lane & 15);
                int c = kk*4 + (lane >> 4), p = c ^ (r & 7);
                af[m][kk] = *(bf16x8*)&As[r*64 + p*8];
            }
#pragma unroll
        for (int n = 0; n < 4; ++n)
#pragma unroll
            for (int kk = 0; kk < 2; ++kk) {
                int r = wn*64 + n*16 + (lane & 15);
                int c = kk*4 + (lane >> 4), p = c ^ (r & 7);
                bfr[n][kk] = *(bf16x8*)&Bs[r*64 + p*8];
            }
#pragma unroll
        for (int kk = 0; kk < 2; ++kk)
#pragma unroll
            for (int m = 0; m < 4; ++m)
#pragma unroll
                for (int n = 0; n < 4; ++n)
                    acc[m][n] = __builtin_amdgcn_mfma_f32_16x16x32_bf16(
                        af[m][kk], bfr[n][kk], acc[m][n], 0, 0, 0);
        __syncthreads();
    }

    const float* w2be = w2b + e*HID_;
#pragma unroll
    for (int n = 0; n < 4; ++n) {
        int col = n0 + wn*64 + n*16 + (lane & 15);
        float bias = w2be[col];
#pragma unroll
        for (int m = 0; m < 4; ++m) {
            int rb2 = t0 + wm*64 + m*16 + (lane >> 4)*4;
#pragma unroll
            for (int i = 0; i < 4; ++i) {
                int t = rb2 + i;
                if (t < ce) {
                    int p   = base + t;
                    float w = gwt[p];
                    atomicAdd(&out[(size_t)gtok[p]*HID_ + col], w * (acc[m][n][i] + bias));
                }
            }
        }
    }
}

// ---------------------------------------------------------------------------
extern "C" void kernel_launch(void* const* d_in, const int* in_sizes, int n_in,
                              void* d_out, int out_size, void* d_ws, size_t ws_size,
                              hipStream_t stream)
{
    const float* x   = (const float*)d_in[0];
    const float* rw  = (const float*)d_in[1];
    const float* rb  = (const float*)d_in[2];
    const float* w1  = (const float*)d_in[3];
    const float* w1b = (const float*)d_in[4];
    const float* w2  = (const float*)d_in[5];
    const float* w2b = (const float*)d_in[6];

    float* out      = (float*)d_out;
    float* topk_out = out + (size_t)M_ * HID_;

    char*  ws   = (char*)d_ws;
    int*   ids  = (int*)  (ws);
    float* wts  = (float*)(ws + 16384);
    int*   gtok = (int*)  (ws + 32768);
    float* gwt  = (float*)(ws + 49152);
    int*   cnt  = (int*)  (ws + 65536);
    int*   off  = (int*)  (ws + 65536 + 128);
    int*   fill = (int*)  (ws + 65536 + 256);
    int*   pos  = (int*)  (ws + 98304);

    const size_t MB = 1024*1024;
    __hip_bfloat16* xb    = (__hip_bfloat16*)(ws + 131072);            // 4 MB
    __hip_bfloat16* h     = (__hip_bfloat16*)(ws + 131072 + 4*MB);     // 16 MB
    float*          dpair = (float*)         (ws + 131072 + 20*MB);    // 32 MB (2 slices)
    __hip_bfloat16* w1bf  = (__hip_bfloat16*)(ws + 131072 + 52*MB);    // 64 MB
    __hip_bfloat16* w2bf  = (__hip_bfloat16*)(ws + 131072 + 116*MB);   // 32 MB
    const bool tier2 = (ws_size >= 131072 + 148*MB);

    hipMemsetAsync(cnt, 0, E_ * sizeof(int), stream);

    cvt_kernel<<<2048, 256, 0, stream>>>(x, xb, (M_*HID_)/4);
    router_kernel<<<M_, 64, 0, stream>>>(x, rw, rb, ids, wts, cnt, topk_out);
    offsets_kernel<<<1, 64, 0, stream>>>(cnt, off, fill);
    scatter_kernel<<<M_/256, 256, 0, stream>>>(ids, wts, fill, gtok, gwt, pos);

    if (tier2) {
        cvt_kernel<<<4096, 256, 0, stream>>>(w1, w1bf, (E_*2*FFN_*HID_)/4);
        cvt_kernel<<<4096, 256, 0, stream>>>(w2, w2bf, (E_*HID_*FFN_)/4);

        dim3 g1(FFN_/64, M_/128, E_);        // (32, 16, 8)
        gemm1_kernel<<<g1, 256, 0, stream>>>(xb, w1bf, w1b, gtok, cnt, off, h);

        dim3 g2(HID_/128, M_/128, 2*E_);     // (8, 16, 16) split-K=2
        gemm2_kernel<<<g2, 256, 0, stream>>>(h, w2bf, w2b, gwt, cnt, off, dpair);

        combine_kernel<<<(M_*HID_)/(256*4), 256, 0, stream>>>(dpair, pos, out);
    } else {
        hipMemsetAsync(out, 0, (size_t)M_ * HID_ * sizeof(float), stream);

        dim3 g1(FFN_/64, M_/128, E_);
        gemm1_rs_kernel<<<g1, 256, 0, stream>>>(xb, w1, w1b, gtok, cnt, off, h);

        dim3 g2(HID_/128, M_/128, E_);
        gemm2_rs_kernel<<<g2, 256, 0, stream>>>(h, w2, w2b, gtok, gwt, cnt, off, out);
    }
}